// Round 1
// baseline (723.111 us; speedup 1.0000x reference)
//
#include <hip/hip_runtime.h>
#include <hip/hip_bf16.h>

// ---------------------------------------------------------------------------
// GIN (3-layer) forward on MI355X. fp32 baseline.
// Pipeline per call:
//   1. CSR build: histogram(deg) -> single-block scan -> scatter
//   2. layer0: agg(x) -> GEMM(64,128,relu) -> GEMM(128,128) -> skip GEMM
//              -> bn_stats -> bn_apply(+skip) = residual
//   3. layer1: agg(relu(res)) -> GEMM -> GEMM -> bn_stats -> bn_apply(+res,relu) = h2
//   4. layer2: agg(h2) -> GEMM(relu) -> GEMM(128,32) -> d_out
// ---------------------------------------------------------------------------

#define HID 128

__global__ void hist_kernel(const int* __restrict__ ei, int* __restrict__ deg, int E) {
    int e = blockIdx.x * blockDim.x + threadIdx.x;
    if (e < E) atomicAdd(&deg[ei[E + e]], 1);
}

// cursor: in = deg, out = exclusive prefix. rowptr: [0, inclusive prefix...]
__launch_bounds__(1024)
__global__ void scan_kernel(int* __restrict__ cursor, int* __restrict__ rowptr, int n) {
    __shared__ int ssum[1024];
    const int tid = threadIdx.x;
    const int chunk = (n + 1023) >> 10;
    const int start = tid * chunk;
    const int end   = min(start + chunk, n);
    int s = 0;
    for (int i = start; i < end; i++) s += cursor[i];
    ssum[tid] = s;
    __syncthreads();
    for (int off = 1; off < 1024; off <<= 1) {
        int t = (tid >= off) ? ssum[tid - off] : 0;
        __syncthreads();
        ssum[tid] += t;
        __syncthreads();
    }
    int run = (tid == 0) ? 0 : ssum[tid - 1];
    for (int i = start; i < end; i++) {
        int d = cursor[i];
        cursor[i] = run;            // exclusive prefix (scatter cursor)
        rowptr[i + 1] = run + d;    // inclusive prefix
        run += d;
    }
    if (tid == 0) rowptr[0] = 0;
}

__global__ void scatter_kernel(const int* __restrict__ ei, int* __restrict__ cursor,
                               int* __restrict__ csr_src, int E) {
    int e = blockIdx.x * blockDim.x + threadIdx.x;
    if (e < E) {
        int s = ei[e];
        int d = ei[E + e];
        int p = atomicAdd(&cursor[d], 1);
        csr_src[p] = s;
    }
}

// z[i] = maybe_relu(h[i]) + sum_{src in row i} maybe_relu(h[src]); one wave per node
template <int D, bool RELUIN>
__global__ void agg_kernel(const float* __restrict__ h, const int* __restrict__ rowptr,
                           const int* __restrict__ csr, float* __restrict__ z, int n) {
    const int wid  = (blockIdx.x * blockDim.x + threadIdx.x) >> 6;
    const int lane = threadIdx.x & 63;
    if (wid >= n) return;
    const int s = rowptr[wid], e = rowptr[wid + 1];
    if constexpr (D == 64) {
        float v = h[(size_t)wid * 64 + lane];
        float acc = RELUIN ? fmaxf(v, 0.f) : v;
        for (int k = s; k < e; k++) {
            float u = h[(size_t)csr[k] * 64 + lane];
            acc += RELUIN ? fmaxf(u, 0.f) : u;
        }
        z[(size_t)wid * 64 + lane] = acc;
    } else {
        const float2* h2 = reinterpret_cast<const float2*>(h);
        float2 v = h2[(size_t)wid * 64 + lane];
        float ax = RELUIN ? fmaxf(v.x, 0.f) : v.x;
        float ay = RELUIN ? fmaxf(v.y, 0.f) : v.y;
        for (int k = s; k < e; k++) {
            float2 u = h2[(size_t)csr[k] * 64 + lane];
            ax += RELUIN ? fmaxf(u.x, 0.f) : u.x;
            ay += RELUIN ? fmaxf(u.y, 0.f) : u.y;
        }
        float2 o; o.x = ax; o.y = ay;
        reinterpret_cast<float2*>(z)[(size_t)wid * 64 + lane] = o;
    }
}

// C[M,NC] = maybe_relu(A[M,K] @ W[K,NC] + bias). Row-major everywhere.
// 256 threads; thread computes 4 rows x 4 cols. BM = (256/(NC/4))*4.
template <int K, int NC, bool RELU>
__launch_bounds__(256)
__global__ void gemm_kernel(const float* __restrict__ A, const float* __restrict__ W,
                            const float* __restrict__ bias, float* __restrict__ C, int M) {
    constexpr int TCOLS = NC / 4;
    constexpr int TROWS = 256 / TCOLS;
    constexpr int BM = TROWS * 4;
    constexpr int K4 = K / 4;
    __shared__ float As[BM][K];
    const int tid = threadIdx.x;
    const int brow = blockIdx.x * BM;

    for (int i = tid; i < BM * K4; i += 256) {
        int r = i / K4, c4 = i % K4;
        int gr = brow + r;
        float4 v = make_float4(0.f, 0.f, 0.f, 0.f);
        if (gr < M) v = reinterpret_cast<const float4*>(A)[(size_t)gr * K4 + c4];
        *reinterpret_cast<float4*>(&As[r][c4 * 4]) = v;
    }
    __syncthreads();

    const int tc = tid % TCOLS, tr = tid / TCOLS;
    const int c0 = tc * 4, r0 = tr * 4;
    float acc[4][4] = {};
#pragma unroll 4
    for (int k = 0; k < K; k++) {
        const float4 w = *reinterpret_cast<const float4*>(&W[k * NC + c0]);
#pragma unroll
        for (int i = 0; i < 4; i++) {
            float a = As[r0 + i][k];
            acc[i][0] += a * w.x;
            acc[i][1] += a * w.y;
            acc[i][2] += a * w.z;
            acc[i][3] += a * w.w;
        }
    }
    const float4 bb = *reinterpret_cast<const float4*>(&bias[c0]);
#pragma unroll
    for (int i = 0; i < 4; i++) {
        int gr = brow + r0 + i;
        if (gr < M) {
            float4 o;
            o.x = acc[i][0] + bb.x;
            o.y = acc[i][1] + bb.y;
            o.z = acc[i][2] + bb.z;
            o.w = acc[i][3] + bb.w;
            if (RELU) {
                o.x = fmaxf(o.x, 0.f); o.y = fmaxf(o.y, 0.f);
                o.z = fmaxf(o.z, 0.f); o.w = fmaxf(o.w, 0.f);
            }
            reinterpret_cast<float4*>(C)[(size_t)gr * (NC / 4) + tc] = o;
        }
    }
}

// per-column sum and sumsq over h[N,128] -> sums[0..127]=sum, sums[128..255]=sumsq
__launch_bounds__(256)
__global__ void bn_stats_kernel(const float* __restrict__ h, float* __restrict__ sums, int n) {
    __shared__ float ls[256], lq[256];
    const int tid = threadIdx.x;
    const int c = tid & 127;
    const int rpb = (n + gridDim.x - 1) / gridDim.x;
    const int rend = min(n, (int)(blockIdx.x + 1) * rpb);
    float s = 0.f, q = 0.f;
    for (int r = blockIdx.x * rpb + (tid >> 7); r < rend; r += 2) {
        float v = h[(size_t)r * HID + c];
        s += v;
        q += v * v;
    }
    ls[tid] = s; lq[tid] = q;
    __syncthreads();
    if (tid < 128) {
        atomicAdd(&sums[c], ls[tid] + ls[tid + 128]);
        atomicAdd(&sums[128 + c], lq[tid] + lq[tid + 128]);
    }
}

// out = maybe_relu( bn(conv) + add )
template <bool RELU>
__global__ void bn_apply_kernel(const float* __restrict__ conv, const float* __restrict__ sums,
                                const float* __restrict__ gamma, const float* __restrict__ beta,
                                const float* __restrict__ add, float* __restrict__ out,
                                int total, int n) {
    int i = blockIdx.x * blockDim.x + threadIdx.x;
    if (i >= total) return;
    int c = i & (HID - 1);
    float m = sums[c] / (float)n;
    float v = sums[HID + c] / (float)n - m * m;
    float sc = gamma[c] * rsqrtf(v + 1e-5f);
    float val = (conv[i] - m) * sc + beta[c] + add[i];
    if (RELU) val = fmaxf(val, 0.f);
    out[i] = val;
}

extern "C" void kernel_launch(void* const* d_in, const int* in_sizes, int n_in,
                              void* d_out, int out_size, void* d_ws, size_t ws_size,
                              hipStream_t stream) {
    const float* x      = (const float*)d_in[0];
    const int*   ei     = (const int*)d_in[1];
    const float* w1_0   = (const float*)d_in[2];
    const float* b1_0   = (const float*)d_in[3];
    const float* w2_0   = (const float*)d_in[4];
    const float* b2_0   = (const float*)d_in[5];
    const float* skip_w = (const float*)d_in[6];
    const float* skip_b = (const float*)d_in[7];
    const float* bn_g0  = (const float*)d_in[8];
    const float* bn_b0  = (const float*)d_in[9];
    const float* w1_1   = (const float*)d_in[10];
    const float* b1_1   = (const float*)d_in[11];
    const float* w2_1   = (const float*)d_in[12];
    const float* b2_1   = (const float*)d_in[13];
    const float* bn_g1  = (const float*)d_in[14];
    const float* bn_b1  = (const float*)d_in[15];
    const float* w1_2   = (const float*)d_in[16];
    const float* b1_2   = (const float*)d_in[17];
    const float* w2_2   = (const float*)d_in[18];
    const float* b2_2   = (const float*)d_in[19];

    const int N = in_sizes[0] / 64;
    const int E = in_sizes[1] / 2;

    char* p = (char*)d_ws;
    auto carve = [&](size_t bytes) -> void* {
        void* q = (void*)p;
        p += (bytes + 255) & ~(size_t)255;
        return q;
    };
    int*   cursor = (int*)carve((size_t)N * 4);          // deg -> excl prefix -> scatter cursor
    int*   rowptr = (int*)carve((size_t)(N + 1) * 4);
    int*   csr    = (int*)carve((size_t)E * 4);
    float* bnsums = (float*)carve(256 * 4);
    const size_t fb = (size_t)N * HID * 4;
    float* bufA = (float*)carve(fb);   // z / conv
    float* bufB = (float*)carve(fb);   // y (post-relu hidden)
    float* bufC = (float*)carve(fb);   // skip, later h2
    float* bufD = (float*)carve(fb);   // residual

    const int EB = (E + 255) / 256;
    const int AGG_B = (N * 64 + 255) / 256;   // one wave per node
    const int G128 = (N + 31) / 32;           // BM=32 for NC=128
    const int G32  = (N + 127) / 128;         // BM=128 for NC=32
    const int EWB = (N * HID + 255) / 256;

    // ---- CSR build (every call: buffers are not preserved across replays)
    hipMemsetAsync(cursor, 0, (size_t)N * 4, stream);
    hist_kernel<<<EB, 256, 0, stream>>>(ei, cursor, E);
    scan_kernel<<<1, 1024, 0, stream>>>(cursor, rowptr, N);
    scatter_kernel<<<EB, 256, 0, stream>>>(ei, cursor, csr, E);

    // ---- layer 0
    agg_kernel<64, false><<<AGG_B, 256, 0, stream>>>(x, rowptr, csr, bufA, N);
    gemm_kernel<64, 128, true ><<<G128, 256, 0, stream>>>(bufA, w1_0, b1_0, bufB, N);
    gemm_kernel<128, 128, false><<<G128, 256, 0, stream>>>(bufB, w2_0, b2_0, bufA, N);
    gemm_kernel<64, 128, false><<<G128, 256, 0, stream>>>(x, skip_w, skip_b, bufC, N);
    hipMemsetAsync(bnsums, 0, 256 * 4, stream);
    bn_stats_kernel<<<256, 256, 0, stream>>>(bufA, bnsums, N);
    bn_apply_kernel<false><<<EWB, 256, 0, stream>>>(bufA, bnsums, bn_g0, bn_b0, bufC, bufD, N * HID, N);

    // ---- layer 1 (input = relu(residual), applied in the gather)
    agg_kernel<128, true><<<AGG_B, 256, 0, stream>>>(bufD, rowptr, csr, bufA, N);
    gemm_kernel<128, 128, true ><<<G128, 256, 0, stream>>>(bufA, w1_1, b1_1, bufB, N);
    gemm_kernel<128, 128, false><<<G128, 256, 0, stream>>>(bufB, w2_1, b2_1, bufA, N);
    hipMemsetAsync(bnsums, 0, 256 * 4, stream);
    bn_stats_kernel<<<256, 256, 0, stream>>>(bufA, bnsums, N);
    bn_apply_kernel<true><<<EWB, 256, 0, stream>>>(bufA, bnsums, bn_g1, bn_b1, bufD, bufC, N * HID, N);

    // ---- layer 2
    agg_kernel<128, false><<<AGG_B, 256, 0, stream>>>(bufC, rowptr, csr, bufA, N);
    gemm_kernel<128, 128, true><<<G128, 256, 0, stream>>>(bufA, w1_2, b1_2, bufB, N);
    gemm_kernel<128, 32, false><<<G32, 256, 0, stream>>>(bufB, w2_2, b2_2, (float*)d_out, N);
}

// Round 2
// 536.308 us; speedup vs baseline: 1.3483x; 1.3483x over previous
//
#include <hip/hip_runtime.h>
#include <hip/hip_bf16.h>

// ---------------------------------------------------------------------------
// GIN (3-layer) forward on MI355X. fp32 baseline, hierarchical CSR scan.
// Pipeline per call:
//   1. CSR build: histogram(deg) -> 3-pass hierarchical scan -> scatter
//   2. layer0: agg(x) -> GEMM(64,128,relu) -> GEMM(128,128) -> skip GEMM
//              -> bn_stats -> bn_apply(+skip) = residual
//   3. layer1: agg(relu(res)) -> GEMM -> GEMM -> bn_stats -> bn_apply(+res,relu)
//   4. layer2: agg -> GEMM(relu) -> GEMM(128,32) -> d_out
// ---------------------------------------------------------------------------

#define HID 128

__global__ void hist_kernel(const int* __restrict__ ei, int* __restrict__ deg, int E) {
    int e = blockIdx.x * blockDim.x + threadIdx.x;
    if (e < E) atomicAdd(&deg[ei[E + e]], 1);
}

// ---- hierarchical exclusive scan of deg[N] -> cursor (excl), rowptr (incl, +leading 0)
__launch_bounds__(256)
__global__ void bsum_kernel(const int* __restrict__ deg, int* __restrict__ bsum, int n) {
    __shared__ int ls[256];
    const int tid = threadIdx.x;
    const int i = blockIdx.x * 256 + tid;
    ls[tid] = (i < n) ? deg[i] : 0;
    __syncthreads();
    for (int off = 128; off > 0; off >>= 1) {
        if (tid < off) ls[tid] += ls[tid + off];
        __syncthreads();
    }
    if (tid == 0) bsum[blockIdx.x] = ls[0];
}

__launch_bounds__(1024)
__global__ void bscan_kernel(int* __restrict__ bsum, int nb) {
    __shared__ int ls[1024];
    const int tid = threadIdx.x;
    const int v = (tid < nb) ? bsum[tid] : 0;
    ls[tid] = v;
    __syncthreads();
    for (int off = 1; off < 1024; off <<= 1) {
        int t = (tid >= off) ? ls[tid - off] : 0;
        __syncthreads();
        ls[tid] += t;
        __syncthreads();
    }
    if (tid < nb) bsum[tid] = ls[tid] - v;   // exclusive
}

__launch_bounds__(256)
__global__ void lscan_kernel(const int* __restrict__ bsum, int* __restrict__ cursor,
                             int* __restrict__ rowptr, int n) {
    __shared__ int ls[256];
    const int tid = threadIdx.x;
    const int i = blockIdx.x * 256 + tid;
    const int v = (i < n) ? cursor[i] : 0;   // cursor currently holds deg
    ls[tid] = v;
    __syncthreads();
    for (int off = 1; off < 256; off <<= 1) {
        int t = (tid >= off) ? ls[tid - off] : 0;
        __syncthreads();
        ls[tid] += t;
        __syncthreads();
    }
    if (i < n) {
        const int incl = ls[tid] + bsum[blockIdx.x];
        cursor[i] = incl - v;       // exclusive prefix (scatter cursor)
        rowptr[i + 1] = incl;
        if (i == 0) rowptr[0] = 0;
    }
}

__global__ void scatter_kernel(const int* __restrict__ ei, int* __restrict__ cursor,
                               int* __restrict__ csr_src, int E) {
    int e = blockIdx.x * blockDim.x + threadIdx.x;
    if (e < E) {
        int s = ei[e];
        int d = ei[E + e];
        int p = atomicAdd(&cursor[d], 1);
        csr_src[p] = s;
    }
}

// z[i] = maybe_relu(h[i]) + sum_{src in row i} maybe_relu(h[src]); one wave per node
template <int D, bool RELUIN>
__global__ void agg_kernel(const float* __restrict__ h, const int* __restrict__ rowptr,
                           const int* __restrict__ csr, float* __restrict__ z, int n) {
    const int wid  = (blockIdx.x * blockDim.x + threadIdx.x) >> 6;
    const int lane = threadIdx.x & 63;
    if (wid >= n) return;
    const int s = rowptr[wid], e = rowptr[wid + 1];
    if constexpr (D == 64) {
        float v = h[(size_t)wid * 64 + lane];
        float acc = RELUIN ? fmaxf(v, 0.f) : v;
#pragma unroll 4
        for (int k = s; k < e; k++) {
            float u = h[(size_t)csr[k] * 64 + lane];
            acc += RELUIN ? fmaxf(u, 0.f) : u;
        }
        z[(size_t)wid * 64 + lane] = acc;
    } else {
        const float2* h2 = reinterpret_cast<const float2*>(h);
        float2 v = h2[(size_t)wid * 64 + lane];
        float ax = RELUIN ? fmaxf(v.x, 0.f) : v.x;
        float ay = RELUIN ? fmaxf(v.y, 0.f) : v.y;
#pragma unroll 4
        for (int k = s; k < e; k++) {
            float2 u = h2[(size_t)csr[k] * 64 + lane];
            ax += RELUIN ? fmaxf(u.x, 0.f) : u.x;
            ay += RELUIN ? fmaxf(u.y, 0.f) : u.y;
        }
        float2 o; o.x = ax; o.y = ay;
        reinterpret_cast<float2*>(z)[(size_t)wid * 64 + lane] = o;
    }
}

// C[M,NC] = maybe_relu(A[M,K] @ W[K,NC] + bias). Row-major everywhere.
// 256 threads; thread computes 4 rows x 4 cols. BM = (256/(NC/4))*4.
template <int K, int NC, bool RELU>
__launch_bounds__(256)
__global__ void gemm_kernel(const float* __restrict__ A, const float* __restrict__ W,
                            const float* __restrict__ bias, float* __restrict__ C, int M) {
    constexpr int TCOLS = NC / 4;
    constexpr int TROWS = 256 / TCOLS;
    constexpr int BM = TROWS * 4;
    constexpr int K4 = K / 4;
    __shared__ float As[BM][K];
    const int tid = threadIdx.x;
    const int brow = blockIdx.x * BM;

    for (int i = tid; i < BM * K4; i += 256) {
        int r = i / K4, c4 = i % K4;
        int gr = brow + r;
        float4 v = make_float4(0.f, 0.f, 0.f, 0.f);
        if (gr < M) v = reinterpret_cast<const float4*>(A)[(size_t)gr * K4 + c4];
        *reinterpret_cast<float4*>(&As[r][c4 * 4]) = v;
    }
    __syncthreads();

    const int tc = tid % TCOLS, tr = tid / TCOLS;
    const int c0 = tc * 4, r0 = tr * 4;
    float acc[4][4] = {};
#pragma unroll 4
    for (int k = 0; k < K; k++) {
        const float4 w = *reinterpret_cast<const float4*>(&W[k * NC + c0]);
#pragma unroll
        for (int i = 0; i < 4; i++) {
            float a = As[r0 + i][k];
            acc[i][0] += a * w.x;
            acc[i][1] += a * w.y;
            acc[i][2] += a * w.z;
            acc[i][3] += a * w.w;
        }
    }
    const float4 bb = *reinterpret_cast<const float4*>(&bias[c0]);
#pragma unroll
    for (int i = 0; i < 4; i++) {
        int gr = brow + r0 + i;
        if (gr < M) {
            float4 o;
            o.x = acc[i][0] + bb.x;
            o.y = acc[i][1] + bb.y;
            o.z = acc[i][2] + bb.z;
            o.w = acc[i][3] + bb.w;
            if (RELU) {
                o.x = fmaxf(o.x, 0.f); o.y = fmaxf(o.y, 0.f);
                o.z = fmaxf(o.z, 0.f); o.w = fmaxf(o.w, 0.f);
            }
            reinterpret_cast<float4*>(C)[(size_t)gr * (NC / 4) + tc] = o;
        }
    }
}

// per-column sum and sumsq over h[N,128] -> sums[0..127]=sum, sums[128..255]=sumsq
__launch_bounds__(256)
__global__ void bn_stats_kernel(const float* __restrict__ h, float* __restrict__ sums, int n) {
    __shared__ float ls[256], lq[256];
    const int tid = threadIdx.x;
    const int c = tid & 127;
    const int rpb = (n + gridDim.x - 1) / gridDim.x;
    const int rend = min(n, (int)(blockIdx.x + 1) * rpb);
    float s = 0.f, q = 0.f;
    for (int r = blockIdx.x * rpb + (tid >> 7); r < rend; r += 2) {
        float v = h[(size_t)r * HID + c];
        s += v;
        q += v * v;
    }
    ls[tid] = s; lq[tid] = q;
    __syncthreads();
    if (tid < 128) {
        atomicAdd(&sums[c], ls[tid] + ls[tid + 128]);
        atomicAdd(&sums[128 + c], lq[tid] + lq[tid + 128]);
    }
}

// out = maybe_relu( bn(conv) + add )
template <bool RELU>
__global__ void bn_apply_kernel(const float* __restrict__ conv, const float* __restrict__ sums,
                                const float* __restrict__ gamma, const float* __restrict__ beta,
                                const float* __restrict__ add, float* __restrict__ out,
                                int total, int n) {
    int i = blockIdx.x * blockDim.x + threadIdx.x;
    if (i >= total) return;
    int c = i & (HID - 1);
    float m = sums[c] / (float)n;
    float v = sums[HID + c] / (float)n - m * m;
    float sc = gamma[c] * rsqrtf(v + 1e-5f);
    float val = (conv[i] - m) * sc + beta[c] + add[i];
    if (RELU) val = fmaxf(val, 0.f);
    out[i] = val;
}

extern "C" void kernel_launch(void* const* d_in, const int* in_sizes, int n_in,
                              void* d_out, int out_size, void* d_ws, size_t ws_size,
                              hipStream_t stream) {
    const float* x      = (const float*)d_in[0];
    const int*   ei     = (const int*)d_in[1];
    const float* w1_0   = (const float*)d_in[2];
    const float* b1_0   = (const float*)d_in[3];
    const float* w2_0   = (const float*)d_in[4];
    const float* b2_0   = (const float*)d_in[5];
    const float* skip_w = (const float*)d_in[6];
    const float* skip_b = (const float*)d_in[7];
    const float* bn_g0  = (const float*)d_in[8];
    const float* bn_b0  = (const float*)d_in[9];
    const float* w1_1   = (const float*)d_in[10];
    const float* b1_1   = (const float*)d_in[11];
    const float* w2_1   = (const float*)d_in[12];
    const float* b2_1   = (const float*)d_in[13];
    const float* bn_g1  = (const float*)d_in[14];
    const float* bn_b1  = (const float*)d_in[15];
    const float* w1_2   = (const float*)d_in[16];
    const float* b1_2   = (const float*)d_in[17];
    const float* w2_2   = (const float*)d_in[18];
    const float* b2_2   = (const float*)d_in[19];

    const int N = in_sizes[0] / 64;
    const int E = in_sizes[1] / 2;

    char* p = (char*)d_ws;
    auto carve = [&](size_t bytes) -> void* {
        void* q = (void*)p;
        p += (bytes + 255) & ~(size_t)255;
        return q;
    };
    int*   cursor = (int*)carve((size_t)N * 4);          // deg -> excl prefix -> scatter cursor
    int*   rowptr = (int*)carve((size_t)(N + 1) * 4);
    int*   csr    = (int*)carve((size_t)E * 4);
    int*   bsum   = (int*)carve(1024 * 4);
    float* bnsums = (float*)carve(256 * 4);
    const size_t fb = (size_t)N * HID * 4;
    float* bufA = (float*)carve(fb);   // z / conv
    float* bufB = (float*)carve(fb);   // y (post-relu hidden)
    float* bufC = (float*)carve(fb);   // skip, later h2
    float* bufD = (float*)carve(fb);   // residual

    const int EB = (E + 255) / 256;
    const int NB = (N + 255) / 256;           // scan blocks
    const int AGG_B = (N * 64 + 255) / 256;   // one wave per node
    const int G128 = (N + 31) / 32;           // BM=32 for NC=128
    const int G32  = (N + 127) / 128;         // BM=128 for NC=32
    const int EWB = (N * HID + 255) / 256;

    // ---- CSR build (every call: buffers are not preserved across replays)
    hipMemsetAsync(cursor, 0, (size_t)N * 4, stream);
    hist_kernel<<<EB, 256, 0, stream>>>(ei, cursor, E);
    bsum_kernel<<<NB, 256, 0, stream>>>(cursor, bsum, N);
    bscan_kernel<<<1, 1024, 0, stream>>>(bsum, NB);
    lscan_kernel<<<NB, 256, 0, stream>>>(bsum, cursor, rowptr, N);
    scatter_kernel<<<EB, 256, 0, stream>>>(ei, cursor, csr, E);

    // ---- layer 0
    agg_kernel<64, false><<<AGG_B, 256, 0, stream>>>(x, rowptr, csr, bufA, N);
    gemm_kernel<64, 128, true ><<<G128, 256, 0, stream>>>(bufA, w1_0, b1_0, bufB, N);
    gemm_kernel<128, 128, false><<<G128, 256, 0, stream>>>(bufB, w2_0, b2_0, bufA, N);
    gemm_kernel<64, 128, false><<<G128, 256, 0, stream>>>(x, skip_w, skip_b, bufC, N);
    hipMemsetAsync(bnsums, 0, 256 * 4, stream);
    bn_stats_kernel<<<256, 256, 0, stream>>>(bufA, bnsums, N);
    bn_apply_kernel<false><<<EWB, 256, 0, stream>>>(bufA, bnsums, bn_g0, bn_b0, bufC, bufD, N * HID, N);

    // ---- layer 1 (input = relu(residual), applied in the gather)
    agg_kernel<128, true><<<AGG_B, 256, 0, stream>>>(bufD, rowptr, csr, bufA, N);
    gemm_kernel<128, 128, true ><<<G128, 256, 0, stream>>>(bufA, w1_1, b1_1, bufB, N);
    gemm_kernel<128, 128, false><<<G128, 256, 0, stream>>>(bufB, w2_1, b2_1, bufA, N);
    hipMemsetAsync(bnsums, 0, 256 * 4, stream);
    bn_stats_kernel<<<256, 256, 0, stream>>>(bufA, bnsums, N);
    bn_apply_kernel<true><<<EWB, 256, 0, stream>>>(bufA, bnsums, bn_g1, bn_b1, bufD, bufC, N * HID, N);

    // ---- layer 2
    agg_kernel<128, false><<<AGG_B, 256, 0, stream>>>(bufC, rowptr, csr, bufA, N);
    gemm_kernel<128, 128, true><<<G128, 256, 0, stream>>>(bufA, w1_2, b1_2, bufB, N);
    gemm_kernel<128, 32, false><<<G32, 256, 0, stream>>>(bufB, w2_2, b2_2, (float*)d_out, N);
}

// Round 3
// 403.720 us; speedup vs baseline: 1.7911x; 1.3284x over previous
//
#include <hip/hip_runtime.h>
#include <hip/hip_bf16.h>

// ---------------------------------------------------------------------------
// GIN (3-layer) forward on MI355X. bf16 gathers + MFMA GEMMs, fp32 BN/residual.
//   1. prep: weights -> bf16 W^T [N][K]; x -> bf16
//   2. CSR build: histogram -> hierarchical scan -> scatter
//   3. per layer: agg(bf16) -> MFMA GEMM(relu,bf16) -> MFMA GEMM(fp32)
//                 -> bn_stats -> bn_apply (fp32 residual + bf16 relu table)
// ---------------------------------------------------------------------------

#define HID 128

typedef __attribute__((ext_vector_type(8))) __bf16 bf16x8;
typedef __attribute__((ext_vector_type(4))) float f32x4;

__device__ __forceinline__ ushort f2b(float f) {
    uint u = __builtin_bit_cast(uint, f);
    u = (u + 0x7fffu + ((u >> 16) & 1u)) >> 16;
    return (ushort)u;
}
__device__ __forceinline__ float b2f(ushort s) {
    return __builtin_bit_cast(float, (uint)s << 16);
}
__device__ __forceinline__ float lo16(uint u) { return __builtin_bit_cast(float, u << 16); }
__device__ __forceinline__ float hi16(uint u) { return __builtin_bit_cast(float, u & 0xffff0000u); }
__device__ __forceinline__ uint packbf(float a, float b) {
    return (uint)f2b(a) | ((uint)f2b(b) << 16);
}

// ---------------- CSR build ----------------
__global__ void hist_kernel(const int* __restrict__ ei, int* __restrict__ deg, int E) {
    int e = blockIdx.x * blockDim.x + threadIdx.x;
    if (e < E) atomicAdd(&deg[ei[E + e]], 1);
}

__launch_bounds__(256)
__global__ void bsum_kernel(const int* __restrict__ deg, int* __restrict__ bsum, int n) {
    __shared__ int ls[256];
    const int tid = threadIdx.x;
    const int i = blockIdx.x * 256 + tid;
    ls[tid] = (i < n) ? deg[i] : 0;
    __syncthreads();
    for (int off = 128; off > 0; off >>= 1) {
        if (tid < off) ls[tid] += ls[tid + off];
        __syncthreads();
    }
    if (tid == 0) bsum[blockIdx.x] = ls[0];
}

__launch_bounds__(1024)
__global__ void bscan_kernel(int* __restrict__ bsum, int nb) {
    __shared__ int ls[1024];
    const int tid = threadIdx.x;
    const int v = (tid < nb) ? bsum[tid] : 0;
    ls[tid] = v;
    __syncthreads();
    for (int off = 1; off < 1024; off <<= 1) {
        int t = (tid >= off) ? ls[tid - off] : 0;
        __syncthreads();
        ls[tid] += t;
        __syncthreads();
    }
    if (tid < nb) bsum[tid] = ls[tid] - v;   // exclusive
}

__launch_bounds__(256)
__global__ void lscan_kernel(const int* __restrict__ bsum, int* __restrict__ cursor,
                             int* __restrict__ rowptr, int n) {
    __shared__ int ls[256];
    const int tid = threadIdx.x;
    const int i = blockIdx.x * 256 + tid;
    const int v = (i < n) ? cursor[i] : 0;   // cursor holds deg
    ls[tid] = v;
    __syncthreads();
    for (int off = 1; off < 256; off <<= 1) {
        int t = (tid >= off) ? ls[tid - off] : 0;
        __syncthreads();
        ls[tid] += t;
        __syncthreads();
    }
    if (i < n) {
        const int incl = ls[tid] + bsum[blockIdx.x];
        cursor[i] = incl - v;
        rowptr[i + 1] = incl;
        if (i == 0) rowptr[0] = 0;
    }
}

__global__ void scatter_kernel(const int* __restrict__ ei, int* __restrict__ cursor,
                               int* __restrict__ csr_src, int E) {
    int e = blockIdx.x * blockDim.x + threadIdx.x;
    if (e < E) {
        int s = ei[e];
        int d = ei[E + e];
        int p = atomicAdd(&cursor[d], 1);
        csr_src[p] = s;
    }
}

// ---------------- prep: weight transpose->bf16, x->bf16 ----------------
struct PrepAll {
    const float* src[7];
    ushort* dst[7];
    int K[7];
    int N[7];
    int off[8];   // block offsets
};

__launch_bounds__(256)
__global__ void wprep_kernel(PrepAll a) {
    const int b = blockIdx.x;
    int m = 0;
    while (m < 6 && b >= a.off[m + 1]) m++;
    const int K = a.K[m], N = a.N[m];
    const int e = (b - a.off[m]) * 256 + threadIdx.x;   // dst-major index: e = n*K + k
    if (e >= K * N) return;
    const int n = e / K, k = e % K;
    a.dst[m][e] = f2b(a.src[m][(size_t)k * N + n]);
}

__global__ void x2bf_kernel(const float* __restrict__ x, ushort* __restrict__ xb, int total4) {
    int i = blockIdx.x * 256 + threadIdx.x;
    if (i < total4) {
        float4 v = reinterpret_cast<const float4*>(x)[i];
        ushort4 o;
        o.x = f2b(v.x); o.y = f2b(v.y); o.z = f2b(v.z); o.w = f2b(v.w);
        reinterpret_cast<ushort4*>(xb)[i] = o;
    }
}

// ---------------- aggregation (bf16 in, bf16 out, fp32 accum) ----------------
template <int D>
__global__ void agg_kernel(const ushort* __restrict__ h, const int* __restrict__ rowptr,
                           const int* __restrict__ csr, ushort* __restrict__ z, int n) {
    const int wid  = (blockIdx.x * blockDim.x + threadIdx.x) >> 6;
    const int lane = threadIdx.x & 63;
    if (wid >= n) return;
    const int s = rowptr[wid], e = rowptr[wid + 1];
    if constexpr (D == 128) {
        const uint* h2 = reinterpret_cast<const uint*>(h);
        uint v = h2[(size_t)wid * 64 + lane];
        float ax = lo16(v), ay = hi16(v);
#pragma unroll 4
        for (int k = s; k < e; k++) {
            uint u = h2[(size_t)csr[k] * 64 + lane];
            ax += lo16(u);
            ay += hi16(u);
        }
        reinterpret_cast<uint*>(z)[(size_t)wid * 64 + lane] = packbf(ax, ay);
    } else {
        float a = b2f(h[(size_t)wid * 64 + lane]);
#pragma unroll 4
        for (int k = s; k < e; k++) a += b2f(h[(size_t)csr[k] * 64 + lane]);
        z[(size_t)wid * 64 + lane] = f2b(a);
    }
}

// ---------------- MFMA GEMM ----------------
// C[M,NC] = maybe_relu(A[M,K](bf16) @ W[K,NC] + bias), W given as Wt[NC][K] bf16.
// Block = 256 thr = 4 waves arranged WR x WC; each wave computes 32x32 (2x2 frags).
template <int K, int NC, int WR, int WC, bool RELU, bool OUTBF>
__launch_bounds__(256)
__global__ void mfma_gemm(const ushort* __restrict__ A, const ushort* __restrict__ Wt,
                          const float* __restrict__ bias, float* __restrict__ Cf,
                          ushort* __restrict__ Cb, int M) {
    constexpr int BM = WR * 32;
    const int tid = threadIdx.x;
    const int w = tid >> 6, lane = tid & 63;
    const int wr = w / WC, wc = w % WC;
    const int rb = blockIdx.x * BM + wr * 32;
    const int cb = blockIdx.y * (WC * 32) + wc * 32;
    const int lr = lane & 15;
    const int lk = (lane >> 4) * 8;

    int ar0 = min(rb + lr, M - 1);
    int ar1 = min(rb + 16 + lr, M - 1);
    const int br0 = cb + lr;
    const int br1 = cb + 16 + lr;

    f32x4 acc00 = {}, acc01 = {}, acc10 = {}, acc11 = {};
#pragma unroll
    for (int k0 = 0; k0 < K; k0 += 32) {
        bf16x8 a0 = *reinterpret_cast<const bf16x8*>(A + (size_t)ar0 * K + k0 + lk);
        bf16x8 a1 = *reinterpret_cast<const bf16x8*>(A + (size_t)ar1 * K + k0 + lk);
        bf16x8 b0 = *reinterpret_cast<const bf16x8*>(Wt + (size_t)br0 * K + k0 + lk);
        bf16x8 b1 = *reinterpret_cast<const bf16x8*>(Wt + (size_t)br1 * K + k0 + lk);
        acc00 = __builtin_amdgcn_mfma_f32_16x16x32_bf16(a0, b0, acc00, 0, 0, 0);
        acc01 = __builtin_amdgcn_mfma_f32_16x16x32_bf16(a0, b1, acc01, 0, 0, 0);
        acc10 = __builtin_amdgcn_mfma_f32_16x16x32_bf16(a1, b0, acc10, 0, 0, 0);
        acc11 = __builtin_amdgcn_mfma_f32_16x16x32_bf16(a1, b1, acc11, 0, 0, 0);
    }

    // D layout: col = lane&15, row = (lane>>4)*4 + j
    const int orow = (lane >> 4) * 4;
    const int col0 = cb + lr, col1 = cb + 16 + lr;
    const float bv0 = bias[col0], bv1 = bias[col1];
    f32x4 accs[2][2] = {{acc00, acc01}, {acc10, acc11}};
#pragma unroll
    for (int m = 0; m < 2; m++) {
#pragma unroll
        for (int j = 0; j < 4; j++) {
            const int row = rb + m * 16 + orow + j;
            if (row < M) {
                float v0 = accs[m][0][j] + bv0;
                float v1 = accs[m][1][j] + bv1;
                if (RELU) { v0 = fmaxf(v0, 0.f); v1 = fmaxf(v1, 0.f); }
                if constexpr (OUTBF) {
                    Cb[(size_t)row * NC + col0] = f2b(v0);
                    Cb[(size_t)row * NC + col1] = f2b(v1);
                } else {
                    Cf[(size_t)row * NC + col0] = v0;
                    Cf[(size_t)row * NC + col1] = v1;
                }
            }
        }
    }
}

// ---------------- batchnorm ----------------
__launch_bounds__(256)
__global__ void bn_stats_kernel(const float* __restrict__ h, float* __restrict__ sums, int n) {
    __shared__ float ls[256], lq[256];
    const int tid = threadIdx.x;
    const int c = tid & 127;
    const int rpb = (n + gridDim.x - 1) / gridDim.x;
    const int rend = min(n, (int)(blockIdx.x + 1) * rpb);
    float s = 0.f, q = 0.f;
    for (int r = blockIdx.x * rpb + (tid >> 7); r < rend; r += 2) {
        float v = h[(size_t)r * HID + c];
        s += v;
        q += v * v;
    }
    ls[tid] = s; lq[tid] = q;
    __syncthreads();
    if (tid < 128) {
        atomicAdd(&sums[c], ls[tid] + ls[tid + 128]);
        atomicAdd(&sums[128 + c], lq[tid] + lq[tid + 128]);
    }
}

// val = bn(conv) + add; optional fp32 residual out; bf16 relu(val) table out
template <bool WRITE_RES>
__global__ void bn_apply_kernel(const float* __restrict__ conv, const float* __restrict__ sums,
                                const float* __restrict__ gamma, const float* __restrict__ beta,
                                const float* __restrict__ add, float* __restrict__ resf,
                                ushort* __restrict__ outb, int total, int n) {
    int i = blockIdx.x * blockDim.x + threadIdx.x;
    if (i >= total) return;
    int c = i & (HID - 1);
    float m = sums[c] / (float)n;
    float v = sums[HID + c] / (float)n - m * m;
    float sc = gamma[c] * rsqrtf(v + 1e-5f);
    float val = (conv[i] - m) * sc + beta[c] + add[i];
    if (WRITE_RES) resf[i] = val;
    outb[i] = f2b(fmaxf(val, 0.f));
}

extern "C" void kernel_launch(void* const* d_in, const int* in_sizes, int n_in,
                              void* d_out, int out_size, void* d_ws, size_t ws_size,
                              hipStream_t stream) {
    const float* x      = (const float*)d_in[0];
    const int*   ei     = (const int*)d_in[1];
    const float* w1_0   = (const float*)d_in[2];
    const float* b1_0   = (const float*)d_in[3];
    const float* w2_0   = (const float*)d_in[4];
    const float* b2_0   = (const float*)d_in[5];
    const float* skip_w = (const float*)d_in[6];
    const float* skip_b = (const float*)d_in[7];
    const float* bn_g0  = (const float*)d_in[8];
    const float* bn_b0  = (const float*)d_in[9];
    const float* w1_1   = (const float*)d_in[10];
    const float* b1_1   = (const float*)d_in[11];
    const float* w2_1   = (const float*)d_in[12];
    const float* b2_1   = (const float*)d_in[13];
    const float* bn_g1  = (const float*)d_in[14];
    const float* bn_b1  = (const float*)d_in[15];
    const float* w1_2   = (const float*)d_in[16];
    const float* b1_2   = (const float*)d_in[17];
    const float* w2_2   = (const float*)d_in[18];
    const float* b2_2   = (const float*)d_in[19];

    const int N = in_sizes[0] / 64;
    const int E = in_sizes[1] / 2;

    char* p = (char*)d_ws;
    auto carve = [&](size_t bytes) -> void* {
        void* q = (void*)p;
        p += (bytes + 255) & ~(size_t)255;
        return q;
    };
    int*   cursor = (int*)carve((size_t)N * 4);
    int*   rowptr = (int*)carve((size_t)(N + 1) * 4);
    int*   csr    = (int*)carve((size_t)E * 4);
    int*   bsum   = (int*)carve(1024 * 4);
    float* bnsums = (float*)carve(256 * 4);
    ushort* w1_0t = (ushort*)carve(64 * 128 * 2);
    ushort* w2_0t = (ushort*)carve(128 * 128 * 2);
    ushort* skwt  = (ushort*)carve(64 * 128 * 2);
    ushort* w1_1t = (ushort*)carve(128 * 128 * 2);
    ushort* w2_1t = (ushort*)carve(128 * 128 * 2);
    ushort* w1_2t = (ushort*)carve(128 * 128 * 2);
    ushort* w2_2t = (ushort*)carve(128 * 32 * 2);
    ushort* x_bf  = (ushort*)carve((size_t)N * 64 * 2);
    ushort* bufZ  = (ushort*)carve((size_t)N * HID * 2);   // agg out (GEMM1 A)
    ushort* bufB  = (ushort*)carve((size_t)N * HID * 2);   // GEMM1 out (GEMM2 A)
    ushort* aggin = (ushort*)carve((size_t)N * HID * 2);   // relu'd bf16 node table
    float* bufA_f = (float*)carve((size_t)N * HID * 4);    // conv (fp32, for BN)
    float* bufC_f = (float*)carve((size_t)N * HID * 4);    // skip -> residual (in place)

    const int EB  = (E + 255) / 256;
    const int NB  = (N + 255) / 256;
    const int AGG_B = (N * 64 + 255) / 256;       // one wave per node
    const int EWB = (N * HID + 255) / 256;
    const dim3 G128((N + 63) / 64, 2);            // WR=2,WC=2: 64x64 tile
    const dim3 G32((N + 127) / 128, 1);           // WR=4,WC=1: 128x32 tile

    // ---- prep (independent of CSR)
    PrepAll pa;
    pa.src[0] = w1_0; pa.dst[0] = w1_0t; pa.K[0] = 64;  pa.N[0] = 128;
    pa.src[1] = w2_0; pa.dst[1] = w2_0t; pa.K[1] = 128; pa.N[1] = 128;
    pa.src[2] = skip_w; pa.dst[2] = skwt; pa.K[2] = 64; pa.N[2] = 128;
    pa.src[3] = w1_1; pa.dst[3] = w1_1t; pa.K[3] = 128; pa.N[3] = 128;
    pa.src[4] = w2_1; pa.dst[4] = w2_1t; pa.K[4] = 128; pa.N[4] = 128;
    pa.src[5] = w1_2; pa.dst[5] = w1_2t; pa.K[5] = 128; pa.N[5] = 128;
    pa.src[6] = w2_2; pa.dst[6] = w2_2t; pa.K[6] = 128; pa.N[6] = 32;
    int off = 0;
    for (int m = 0; m < 7; m++) { pa.off[m] = off; off += (pa.K[m] * pa.N[m]) / 256; }
    pa.off[7] = off;
    wprep_kernel<<<off, 256, 0, stream>>>(pa);
    x2bf_kernel<<<(N * 64 / 4 + 255) / 256, 256, 0, stream>>>(x, x_bf, N * 64 / 4);

    // ---- CSR build
    hipMemsetAsync(cursor, 0, (size_t)N * 4, stream);
    hist_kernel<<<EB, 256, 0, stream>>>(ei, cursor, E);
    bsum_kernel<<<NB, 256, 0, stream>>>(cursor, bsum, N);
    bscan_kernel<<<1, 1024, 0, stream>>>(bsum, NB);
    lscan_kernel<<<NB, 256, 0, stream>>>(bsum, cursor, rowptr, N);
    scatter_kernel<<<EB, 256, 0, stream>>>(ei, cursor, csr, E);

    // ---- layer 0
    agg_kernel<64><<<AGG_B, 256, 0, stream>>>(x_bf, rowptr, csr, bufZ, N);
    mfma_gemm<64, 128, 2, 2, true, true><<<G128, 256, 0, stream>>>(bufZ, w1_0t, b1_0, nullptr, bufB, N);
    mfma_gemm<128, 128, 2, 2, false, false><<<G128, 256, 0, stream>>>(bufB, w2_0t, b2_0, bufA_f, nullptr, N);
    mfma_gemm<64, 128, 2, 2, false, false><<<G128, 256, 0, stream>>>(x_bf, skwt, skip_b, bufC_f, nullptr, N);
    hipMemsetAsync(bnsums, 0, 256 * 4, stream);
    bn_stats_kernel<<<256, 256, 0, stream>>>(bufA_f, bnsums, N);
    // residual (fp32, in place into bufC_f) + bf16 relu table for layer-1 agg
    bn_apply_kernel<true><<<EWB, 256, 0, stream>>>(bufA_f, bnsums, bn_g0, bn_b0, bufC_f, bufC_f, aggin, N * HID, N);

    // ---- layer 1
    agg_kernel<128><<<AGG_B, 256, 0, stream>>>(aggin, rowptr, csr, bufZ, N);
    mfma_gemm<128, 128, 2, 2, true, true><<<G128, 256, 0, stream>>>(bufZ, w1_1t, b1_1, nullptr, bufB, N);
    mfma_gemm<128, 128, 2, 2, false, false><<<G128, 256, 0, stream>>>(bufB, w2_1t, b2_1, bufA_f, nullptr, N);
    hipMemsetAsync(bnsums, 0, 256 * 4, stream);
    bn_stats_kernel<<<256, 256, 0, stream>>>(bufA_f, bnsums, N);
    bn_apply_kernel<false><<<EWB, 256, 0, stream>>>(bufA_f, bnsums, bn_g1, bn_b1, bufC_f, nullptr, aggin, N * HID, N);

    // ---- layer 2
    agg_kernel<128><<<AGG_B, 256, 0, stream>>>(aggin, rowptr, csr, bufZ, N);
    mfma_gemm<128, 128, 2, 2, true, true><<<G128, 256, 0, stream>>>(bufZ, w1_2t, b1_2, nullptr, bufB, N);
    mfma_gemm<128, 32, 4, 1, false, false><<<G32, 256, 0, stream>>>(bufB, w2_2t, b2_2, (float*)d_out, nullptr, N);
}

// Round 4
// 392.714 us; speedup vs baseline: 1.8413x; 1.0280x over previous
//
#include <hip/hip_runtime.h>
#include <hip/hip_bf16.h>

// ---------------------------------------------------------------------------
// GIN (3-layer) forward on MI355X. bf16 gathers + MFMA GEMMs, fp32 BN/residual.
// CSR build uses dst-partitioned hist/scatter (8 partitions ~ XCDs) so the
// random 4B writes/atomics stay XCD-L2-local instead of thrashing cross-XCD.
// ---------------------------------------------------------------------------

#define HID 128
#define NPART 8
#define BLK_PER_PART 128

typedef __attribute__((ext_vector_type(8))) __bf16 bf16x8;
typedef __attribute__((ext_vector_type(4))) float f32x4;

__device__ __forceinline__ ushort f2b(float f) {
    uint u = __builtin_bit_cast(uint, f);
    u = (u + 0x7fffu + ((u >> 16) & 1u)) >> 16;
    return (ushort)u;
}
__device__ __forceinline__ float b2f(ushort s) {
    return __builtin_bit_cast(float, (uint)s << 16);
}
__device__ __forceinline__ float lo16(uint u) { return __builtin_bit_cast(float, u << 16); }
__device__ __forceinline__ float hi16(uint u) { return __builtin_bit_cast(float, u & 0xffff0000u); }
__device__ __forceinline__ uint packbf(float a, float b) {
    return (uint)f2b(a) | ((uint)f2b(b) << 16);
}

// ---------------- CSR build (dst-partitioned) ----------------
// partition p handles dst in [p*chunk, (p+1)*chunk); its blocks scan all edges.
__launch_bounds__(256)
__global__ void hist_part_kernel(const int* __restrict__ ei, int* __restrict__ deg,
                                 int E, int chunk) {
    const int part = blockIdx.x & (NPART - 1);
    const int blk  = blockIdx.x >> 3;
    const int lo = part * chunk, hi = lo + chunk;
    const int epb = (E + BLK_PER_PART - 1) / BLK_PER_PART;
    const int e0 = blk * epb, e1 = min(e0 + epb, E);
    for (int e = e0 + threadIdx.x; e < e1; e += 256) {
        int d = ei[E + e];
        if (d >= lo && d < hi) atomicAdd(&deg[d], 1);
    }
}

__launch_bounds__(256)
__global__ void scatter_part_kernel(const int* __restrict__ ei, int* __restrict__ cursor,
                                    int* __restrict__ csr_src, int E, int chunk) {
    const int part = blockIdx.x & (NPART - 1);
    const int blk  = blockIdx.x >> 3;
    const int lo = part * chunk, hi = lo + chunk;
    const int epb = (E + BLK_PER_PART - 1) / BLK_PER_PART;
    const int e0 = blk * epb, e1 = min(e0 + epb, E);
    for (int e = e0 + threadIdx.x; e < e1; e += 256) {
        int d = ei[E + e];
        if (d >= lo && d < hi) {
            int p = atomicAdd(&cursor[d], 1);
            csr_src[p] = ei[e];
        }
    }
}

// ---- hierarchical exclusive scan of deg[N] -> cursor (excl), rowptr (incl)
__launch_bounds__(256)
__global__ void bsum_kernel(const int* __restrict__ deg, int* __restrict__ bsum, int n) {
    __shared__ int ls[256];
    const int tid = threadIdx.x;
    const int i = blockIdx.x * 256 + tid;
    ls[tid] = (i < n) ? deg[i] : 0;
    __syncthreads();
    for (int off = 128; off > 0; off >>= 1) {
        if (tid < off) ls[tid] += ls[tid + off];
        __syncthreads();
    }
    if (tid == 0) bsum[blockIdx.x] = ls[0];
}

__launch_bounds__(1024)
__global__ void bscan_kernel(int* __restrict__ bsum, int nb) {
    __shared__ int ls[1024];
    const int tid = threadIdx.x;
    const int v = (tid < nb) ? bsum[tid] : 0;
    ls[tid] = v;
    __syncthreads();
    for (int off = 1; off < 1024; off <<= 1) {
        int t = (tid >= off) ? ls[tid - off] : 0;
        __syncthreads();
        ls[tid] += t;
        __syncthreads();
    }
    if (tid < nb) bsum[tid] = ls[tid] - v;   // exclusive
}

__launch_bounds__(256)
__global__ void lscan_kernel(const int* __restrict__ bsum, int* __restrict__ cursor,
                             int* __restrict__ rowptr, int n) {
    __shared__ int ls[256];
    const int tid = threadIdx.x;
    const int i = blockIdx.x * 256 + tid;
    const int v = (i < n) ? cursor[i] : 0;   // cursor holds deg
    ls[tid] = v;
    __syncthreads();
    for (int off = 1; off < 256; off <<= 1) {
        int t = (tid >= off) ? ls[tid - off] : 0;
        __syncthreads();
        ls[tid] += t;
        __syncthreads();
    }
    if (i < n) {
        const int incl = ls[tid] + bsum[blockIdx.x];
        cursor[i] = incl - v;
        rowptr[i + 1] = incl;
        if (i == 0) rowptr[0] = 0;
    }
}

// ---------------- prep: weight transpose->bf16, x->bf16 ----------------
struct PrepAll {
    const float* src[7];
    ushort* dst[7];
    int K[7];
    int N[7];
    int off[8];   // block offsets
};

__launch_bounds__(256)
__global__ void wprep_kernel(PrepAll a) {
    const int b = blockIdx.x;
    int m = 0;
    while (m < 6 && b >= a.off[m + 1]) m++;
    const int K = a.K[m], N = a.N[m];
    const int e = (b - a.off[m]) * 256 + threadIdx.x;   // dst-major index: e = n*K + k
    if (e >= K * N) return;
    const int n = e / K, k = e % K;
    a.dst[m][e] = f2b(a.src[m][(size_t)k * N + n]);
}

__global__ void x2bf_kernel(const float* __restrict__ x, ushort* __restrict__ xb, int total4) {
    int i = blockIdx.x * 256 + threadIdx.x;
    if (i < total4) {
        float4 v = reinterpret_cast<const float4*>(x)[i];
        ushort4 o;
        o.x = f2b(v.x); o.y = f2b(v.y); o.z = f2b(v.z); o.w = f2b(v.w);
        reinterpret_cast<ushort4*>(xb)[i] = o;
    }
}

// ---------------- aggregation (bf16 in, bf16 out, fp32 accum) ----------------
template <int D>
__global__ void agg_kernel(const ushort* __restrict__ h, const int* __restrict__ rowptr,
                           const int* __restrict__ csr, ushort* __restrict__ z, int n) {
    const int wid  = (blockIdx.x * blockDim.x + threadIdx.x) >> 6;
    const int lane = threadIdx.x & 63;
    if (wid >= n) return;
    const int s = rowptr[wid], e = rowptr[wid + 1];
    if constexpr (D == 128) {
        const uint* h2 = reinterpret_cast<const uint*>(h);
        uint v = h2[(size_t)wid * 64 + lane];
        float ax = lo16(v), ay = hi16(v);
#pragma unroll 4
        for (int k = s; k < e; k++) {
            uint u = h2[(size_t)csr[k] * 64 + lane];
            ax += lo16(u);
            ay += hi16(u);
        }
        reinterpret_cast<uint*>(z)[(size_t)wid * 64 + lane] = packbf(ax, ay);
    } else {
        float a = b2f(h[(size_t)wid * 64 + lane]);
#pragma unroll 4
        for (int k = s; k < e; k++) a += b2f(h[(size_t)csr[k] * 64 + lane]);
        z[(size_t)wid * 64 + lane] = f2b(a);
    }
}

// ---------------- MFMA GEMM ----------------
// C[M,NC] = maybe_relu(A[M,K](bf16) @ W[K,NC] + bias), W given as Wt[NC][K] bf16.
template <int K, int NC, int WR, int WC, bool RELU, bool OUTBF>
__launch_bounds__(256)
__global__ void mfma_gemm(const ushort* __restrict__ A, const ushort* __restrict__ Wt,
                          const float* __restrict__ bias, float* __restrict__ Cf,
                          ushort* __restrict__ Cb, int M) {
    constexpr int BM = WR * 32;
    const int tid = threadIdx.x;
    const int w = tid >> 6, lane = tid & 63;
    const int wr = w / WC, wc = w % WC;
    const int rb = blockIdx.x * BM + wr * 32;
    const int cb = blockIdx.y * (WC * 32) + wc * 32;
    const int lr = lane & 15;
    const int lk = (lane >> 4) * 8;

    int ar0 = min(rb + lr, M - 1);
    int ar1 = min(rb + 16 + lr, M - 1);
    const int br0 = cb + lr;
    const int br1 = cb + 16 + lr;

    f32x4 acc00 = {}, acc01 = {}, acc10 = {}, acc11 = {};
#pragma unroll
    for (int k0 = 0; k0 < K; k0 += 32) {
        bf16x8 a0 = *reinterpret_cast<const bf16x8*>(A + (size_t)ar0 * K + k0 + lk);
        bf16x8 a1 = *reinterpret_cast<const bf16x8*>(A + (size_t)ar1 * K + k0 + lk);
        bf16x8 b0 = *reinterpret_cast<const bf16x8*>(Wt + (size_t)br0 * K + k0 + lk);
        bf16x8 b1 = *reinterpret_cast<const bf16x8*>(Wt + (size_t)br1 * K + k0 + lk);
        acc00 = __builtin_amdgcn_mfma_f32_16x16x32_bf16(a0, b0, acc00, 0, 0, 0);
        acc01 = __builtin_amdgcn_mfma_f32_16x16x32_bf16(a0, b1, acc01, 0, 0, 0);
        acc10 = __builtin_amdgcn_mfma_f32_16x16x32_bf16(a1, b0, acc10, 0, 0, 0);
        acc11 = __builtin_amdgcn_mfma_f32_16x16x32_bf16(a1, b1, acc11, 0, 0, 0);
    }

    // D layout: col = lane&15, row = (lane>>4)*4 + j
    const int orow = (lane >> 4) * 4;
    const int col0 = cb + lr, col1 = cb + 16 + lr;
    const float bv0 = bias[col0], bv1 = bias[col1];
    f32x4 accs[2][2] = {{acc00, acc01}, {acc10, acc11}};
#pragma unroll
    for (int m = 0; m < 2; m++) {
#pragma unroll
        for (int j = 0; j < 4; j++) {
            const int row = rb + m * 16 + orow + j;
            if (row < M) {
                float v0 = accs[m][0][j] + bv0;
                float v1 = accs[m][1][j] + bv1;
                if (RELU) { v0 = fmaxf(v0, 0.f); v1 = fmaxf(v1, 0.f); }
                if constexpr (OUTBF) {
                    Cb[(size_t)row * NC + col0] = f2b(v0);
                    Cb[(size_t)row * NC + col1] = f2b(v1);
                } else {
                    Cf[(size_t)row * NC + col0] = v0;
                    Cf[(size_t)row * NC + col1] = v1;
                }
            }
        }
    }
}

// ---------------- batchnorm ----------------
__launch_bounds__(256)
__global__ void bn_stats_kernel(const float* __restrict__ h, float* __restrict__ sums, int n) {
    __shared__ float ls[256], lq[256];
    const int tid = threadIdx.x;
    const int c = tid & 127;
    const int rpb = (n + gridDim.x - 1) / gridDim.x;
    const int rend = min(n, (int)(blockIdx.x + 1) * rpb);
    float s = 0.f, q = 0.f;
    for (int r = blockIdx.x * rpb + (tid >> 7); r < rend; r += 2) {
        float v = h[(size_t)r * HID + c];
        s += v;
        q += v * v;
    }
    ls[tid] = s; lq[tid] = q;
    __syncthreads();
    if (tid < 128) {
        atomicAdd(&sums[c], ls[tid] + ls[tid + 128]);
        atomicAdd(&sums[128 + c], lq[tid] + lq[tid + 128]);
    }
}

// val = bn(conv) + add; optional fp32 residual out; bf16 relu(val) table out
template <bool WRITE_RES>
__global__ void bn_apply_kernel(const float* __restrict__ conv, const float* __restrict__ sums,
                                const float* __restrict__ gamma, const float* __restrict__ beta,
                                const float* __restrict__ add, float* __restrict__ resf,
                                ushort* __restrict__ outb, int total, int n) {
    int i = blockIdx.x * blockDim.x + threadIdx.x;
    if (i >= total) return;
    int c = i & (HID - 1);
    float m = sums[c] / (float)n;
    float v = sums[HID + c] / (float)n - m * m;
    float sc = gamma[c] * rsqrtf(v + 1e-5f);
    float val = (conv[i] - m) * sc + beta[c] + add[i];
    if (WRITE_RES) resf[i] = val;
    outb[i] = f2b(fmaxf(val, 0.f));
}

extern "C" void kernel_launch(void* const* d_in, const int* in_sizes, int n_in,
                              void* d_out, int out_size, void* d_ws, size_t ws_size,
                              hipStream_t stream) {
    const float* x      = (const float*)d_in[0];
    const int*   ei     = (const int*)d_in[1];
    const float* w1_0   = (const float*)d_in[2];
    const float* b1_0   = (const float*)d_in[3];
    const float* w2_0   = (const float*)d_in[4];
    const float* b2_0   = (const float*)d_in[5];
    const float* skip_w = (const float*)d_in[6];
    const float* skip_b = (const float*)d_in[7];
    const float* bn_g0  = (const float*)d_in[8];
    const float* bn_b0  = (const float*)d_in[9];
    const float* w1_1   = (const float*)d_in[10];
    const float* b1_1   = (const float*)d_in[11];
    const float* w2_1   = (const float*)d_in[12];
    const float* b2_1   = (const float*)d_in[13];
    const float* bn_g1  = (const float*)d_in[14];
    const float* bn_b1  = (const float*)d_in[15];
    const float* w1_2   = (const float*)d_in[16];
    const float* b1_2   = (const float*)d_in[17];
    const float* w2_2   = (const float*)d_in[18];
    const float* b2_2   = (const float*)d_in[19];

    const int N = in_sizes[0] / 64;
    const int E = in_sizes[1] / 2;

    char* p = (char*)d_ws;
    auto carve = [&](size_t bytes) -> void* {
        void* q = (void*)p;
        p += (bytes + 255) & ~(size_t)255;
        return q;
    };
    int*   cursor = (int*)carve((size_t)N * 4);
    int*   rowptr = (int*)carve((size_t)(N + 1) * 4);
    int*   csr    = (int*)carve((size_t)E * 4);
    int*   bsum   = (int*)carve(1024 * 4);
    float* bnsums = (float*)carve(256 * 4);
    ushort* w1_0t = (ushort*)carve(64 * 128 * 2);
    ushort* w2_0t = (ushort*)carve(128 * 128 * 2);
    ushort* skwt  = (ushort*)carve(64 * 128 * 2);
    ushort* w1_1t = (ushort*)carve(128 * 128 * 2);
    ushort* w2_1t = (ushort*)carve(128 * 128 * 2);
    ushort* w1_2t = (ushort*)carve(128 * 128 * 2);
    ushort* w2_2t = (ushort*)carve(128 * 32 * 2);
    ushort* x_bf  = (ushort*)carve((size_t)N * 64 * 2);
    ushort* bufZ  = (ushort*)carve((size_t)N * HID * 2);   // agg out (GEMM1 A)
    ushort* bufB  = (ushort*)carve((size_t)N * HID * 2);   // GEMM1 out (GEMM2 A)
    ushort* aggin = (ushort*)carve((size_t)N * HID * 2);   // relu'd bf16 node table
    float* bufA_f = (float*)carve((size_t)N * HID * 4);    // conv (fp32, for BN)
    float* bufC_f = (float*)carve((size_t)N * HID * 4);    // skip -> residual (in place)

    const int NB  = (N + 255) / 256;
    const int AGG_B = (N * 64 + 255) / 256;       // one wave per node
    const int EWB = (N * HID + 255) / 256;
    const int PART_G = NPART * BLK_PER_PART;
    const int pchunk = (N + NPART - 1) / NPART;
    const dim3 G128((N + 63) / 64, 2);            // WR=2,WC=2: 64x64 tile
    const dim3 G32((N + 127) / 128, 1);           // WR=4,WC=1: 128x32 tile

    // ---- prep (independent of CSR)
    PrepAll pa;
    pa.src[0] = w1_0; pa.dst[0] = w1_0t; pa.K[0] = 64;  pa.N[0] = 128;
    pa.src[1] = w2_0; pa.dst[1] = w2_0t; pa.K[1] = 128; pa.N[1] = 128;
    pa.src[2] = skip_w; pa.dst[2] = skwt; pa.K[2] = 64; pa.N[2] = 128;
    pa.src[3] = w1_1; pa.dst[3] = w1_1t; pa.K[3] = 128; pa.N[3] = 128;
    pa.src[4] = w2_1; pa.dst[4] = w2_1t; pa.K[4] = 128; pa.N[4] = 128;
    pa.src[5] = w1_2; pa.dst[5] = w1_2t; pa.K[5] = 128; pa.N[5] = 128;
    pa.src[6] = w2_2; pa.dst[6] = w2_2t; pa.K[6] = 128; pa.N[6] = 32;
    int off = 0;
    for (int m = 0; m < 7; m++) { pa.off[m] = off; off += (pa.K[m] * pa.N[m]) / 256; }
    pa.off[7] = off;
    wprep_kernel<<<off, 256, 0, stream>>>(pa);
    x2bf_kernel<<<(N * 64 / 4 + 255) / 256, 256, 0, stream>>>(x, x_bf, N * 64 / 4);

    // ---- CSR build
    hipMemsetAsync(cursor, 0, (size_t)N * 4, stream);
    hist_part_kernel<<<PART_G, 256, 0, stream>>>(ei, cursor, E, pchunk);
    bsum_kernel<<<NB, 256, 0, stream>>>(cursor, bsum, N);
    bscan_kernel<<<1, 1024, 0, stream>>>(bsum, NB);
    lscan_kernel<<<NB, 256, 0, stream>>>(bsum, cursor, rowptr, N);
    scatter_part_kernel<<<PART_G, 256, 0, stream>>>(ei, cursor, csr, E, pchunk);

    // ---- layer 0
    agg_kernel<64><<<AGG_B, 256, 0, stream>>>(x_bf, rowptr, csr, bufZ, N);
    mfma_gemm<64, 128, 2, 2, true, true><<<G128, 256, 0, stream>>>(bufZ, w1_0t, b1_0, nullptr, bufB, N);
    mfma_gemm<128, 128, 2, 2, false, false><<<G128, 256, 0, stream>>>(bufB, w2_0t, b2_0, bufA_f, nullptr, N);
    mfma_gemm<64, 128, 2, 2, false, false><<<G128, 256, 0, stream>>>(x_bf, skwt, skip_b, bufC_f, nullptr, N);
    hipMemsetAsync(bnsums, 0, 256 * 4, stream);
    bn_stats_kernel<<<256, 256, 0, stream>>>(bufA_f, bnsums, N);
    bn_apply_kernel<true><<<EWB, 256, 0, stream>>>(bufA_f, bnsums, bn_g0, bn_b0, bufC_f, bufC_f, aggin, N * HID, N);

    // ---- layer 1
    agg_kernel<128><<<AGG_B, 256, 0, stream>>>(aggin, rowptr, csr, bufZ, N);
    mfma_gemm<128, 128, 2, 2, true, true><<<G128, 256, 0, stream>>>(bufZ, w1_1t, b1_1, nullptr, bufB, N);
    mfma_gemm<128, 128, 2, 2, false, false><<<G128, 256, 0, stream>>>(bufB, w2_1t, b2_1, bufA_f, nullptr, N);
    hipMemsetAsync(bnsums, 0, 256 * 4, stream);
    bn_stats_kernel<<<256, 256, 0, stream>>>(bufA_f, bnsums, N);
    bn_apply_kernel<false><<<EWB, 256, 0, stream>>>(bufA_f, bnsums, bn_g1, bn_b1, bufC_f, nullptr, aggin, N * HID, N);

    // ---- layer 2
    agg_kernel<128><<<AGG_B, 256, 0, stream>>>(aggin, rowptr, csr, bufZ, N);
    mfma_gemm<128, 128, 2, 2, true, true><<<G128, 256, 0, stream>>>(bufZ, w1_2t, b1_2, nullptr, bufB, N);
    mfma_gemm<128, 32, 4, 1, false, false><<<G32, 256, 0, stream>>>(bufB, w2_2t, b2_2, (float*)d_out, nullptr, N);
}

// Round 5
// 356.523 us; speedup vs baseline: 2.0282x; 1.1015x over previous
//
#include <hip/hip_runtime.h>
#include <hip/hip_bf16.h>

// ---------------------------------------------------------------------------
// GIN (3-layer) forward on MI355X.
//  - CSR build: 3-pass edge bucketing (count -> scan -> distribute) into 8
//    dst-range partitions, then partition-local hist/scan/scatter so random
//    atomics/writes stay XCD-L2-local and edges are read once.
//  - Per layer: ONE fused kernel (agg gather -> MFMA GEMM1+relu -> MFMA GEMM2)
//    using XOR-swizzled LDS tiles; conv out fp32. BN stats/apply separate.
// ---------------------------------------------------------------------------

#define HID 128
#define NPART 8
#define ABLK 256      // blocks in edge-bucketing passes
#define BBLK 128      // blocks per partition in hist/scatter

typedef __attribute__((ext_vector_type(8))) __bf16 bf16x8;
typedef __attribute__((ext_vector_type(4))) float f32x4;

__device__ __forceinline__ ushort f2b(float f) {
    uint u = __builtin_bit_cast(uint, f);
    u = (u + 0x7fffu + ((u >> 16) & 1u)) >> 16;
    return (ushort)u;
}
__device__ __forceinline__ float b2f(ushort s) {
    return __builtin_bit_cast(float, (uint)s << 16);
}
__device__ __forceinline__ float lo16(uint u) { return __builtin_bit_cast(float, u << 16); }
__device__ __forceinline__ float hi16(uint u) { return __builtin_bit_cast(float, u & 0xffff0000u); }
__device__ __forceinline__ uint packbf(float a, float b) {
    return (uint)f2b(a) | ((uint)f2b(b) << 16);
}

// ---------------- CSR build ----------------
// Pass A1: per-(block, partition) edge counts.
__launch_bounds__(256)
__global__ void ecount_kernel(const int* __restrict__ ei, int* __restrict__ bc,
                              int E, int pchunk) {
    __shared__ int cnt[NPART];
    if (threadIdx.x < NPART) cnt[threadIdx.x] = 0;
    __syncthreads();
    const int epb = (E + ABLK - 1) / ABLK;
    const int e0 = blockIdx.x * epb, e1 = min(e0 + epb, E);
    for (int e = e0 + threadIdx.x; e < e1; e += 256) {
        int d = ei[E + e];
        atomicAdd(&cnt[d / pchunk], 1);
    }
    __syncthreads();
    if (threadIdx.x < NPART) bc[threadIdx.x * ABLK + blockIdx.x] = cnt[threadIdx.x];
}

// Pass A2: exclusive scan of the 8*ABLK counts (partition-major).
__launch_bounds__(1024)
__global__ void escan_kernel(int* __restrict__ bc) {
    __shared__ int ls[1024];
    const int t = threadIdx.x;
    const int v0 = bc[2 * t], v1 = bc[2 * t + 1];
    ls[t] = v0 + v1;
    __syncthreads();
    for (int off = 1; off < 1024; off <<= 1) {
        int tmp = (t >= off) ? ls[t - off] : 0;
        __syncthreads();
        ls[t] += tmp;
        __syncthreads();
    }
    const int excl = ls[t] - (v0 + v1);
    bc[2 * t] = excl;
    bc[2 * t + 1] = excl + v0;
}

// Pass A3: redistribute edges into partition-contiguous int2(src,dst) buffer.
__launch_bounds__(256)
__global__ void edist_kernel(const int* __restrict__ ei, const int* __restrict__ bc,
                             int2* __restrict__ ebuf, int E, int pchunk) {
    __shared__ int base[NPART];
    if (threadIdx.x < NPART) base[threadIdx.x] = bc[threadIdx.x * ABLK + blockIdx.x];
    __syncthreads();
    const int epb = (E + ABLK - 1) / ABLK;
    const int e0 = blockIdx.x * epb, e1 = min(e0 + epb, E);
    for (int e = e0 + threadIdx.x; e < e1; e += 256) {
        int s = ei[e], d = ei[E + e];
        int pos = atomicAdd(&base[d / pchunk], 1);
        ebuf[pos] = make_int2(s, d);
    }
}

// Pass B: partition-local histogram (blockIdx&7 = partition -> XCD-local).
__launch_bounds__(256)
__global__ void histp_kernel(const int2* __restrict__ ebuf, const int* __restrict__ bc,
                             int* __restrict__ deg, int E) {
    const int part = blockIdx.x & (NPART - 1);
    const int blk  = blockIdx.x >> 3;
    const int pstart = bc[part * ABLK];
    const int pend = (part == NPART - 1) ? E : bc[(part + 1) * ABLK];
    const int epb = (pend - pstart + BBLK - 1) / BBLK;
    const int e0 = pstart + blk * epb, e1 = min(e0 + epb, pend);
    for (int e = e0 + threadIdx.x; e < e1; e += 256)
        atomicAdd(&deg[ebuf[e].y], 1);
}

__launch_bounds__(256)
__global__ void scatterp_kernel(const int2* __restrict__ ebuf, const int* __restrict__ bc,
                                int* __restrict__ cursor, int* __restrict__ csr_src, int E) {
    const int part = blockIdx.x & (NPART - 1);
    const int blk  = blockIdx.x >> 3;
    const int pstart = bc[part * ABLK];
    const int pend = (part == NPART - 1) ? E : bc[(part + 1) * ABLK];
    const int epb = (pend - pstart + BBLK - 1) / BBLK;
    const int e0 = pstart + blk * epb, e1 = min(e0 + epb, pend);
    for (int e = e0 + threadIdx.x; e < e1; e += 256) {
        int2 ed = ebuf[e];
        int p = atomicAdd(&cursor[ed.y], 1);
        csr_src[p] = ed.x;
    }
}

// ---- hierarchical exclusive scan of deg[N] -> cursor (excl), rowptr (incl)
__launch_bounds__(256)
__global__ void bsum_kernel(const int* __restrict__ deg, int* __restrict__ bsum, int n) {
    __shared__ int ls[256];
    const int tid = threadIdx.x;
    const int i = blockIdx.x * 256 + tid;
    ls[tid] = (i < n) ? deg[i] : 0;
    __syncthreads();
    for (int off = 128; off > 0; off >>= 1) {
        if (tid < off) ls[tid] += ls[tid + off];
        __syncthreads();
    }
    if (tid == 0) bsum[blockIdx.x] = ls[0];
}

__launch_bounds__(1024)
__global__ void bscan_kernel(int* __restrict__ bsum, int nb) {
    __shared__ int ls[1024];
    const int tid = threadIdx.x;
    const int v = (tid < nb) ? bsum[tid] : 0;
    ls[tid] = v;
    __syncthreads();
    for (int off = 1; off < 1024; off <<= 1) {
        int t = (tid >= off) ? ls[tid - off] : 0;
        __syncthreads();
        ls[tid] += t;
        __syncthreads();
    }
    if (tid < nb) bsum[tid] = ls[tid] - v;   // exclusive
}

__launch_bounds__(256)
__global__ void lscan_kernel(const int* __restrict__ bsum, int* __restrict__ cursor,
                             int* __restrict__ rowptr, int n) {
    __shared__ int ls[256];
    const int tid = threadIdx.x;
    const int i = blockIdx.x * 256 + tid;
    const int v = (i < n) ? cursor[i] : 0;   // cursor holds deg
    ls[tid] = v;
    __syncthreads();
    for (int off = 1; off < 256; off <<= 1) {
        int t = (tid >= off) ? ls[tid - off] : 0;
        __syncthreads();
        ls[tid] += t;
        __syncthreads();
    }
    if (i < n) {
        const int incl = ls[tid] + bsum[blockIdx.x];
        cursor[i] = incl - v;
        rowptr[i + 1] = incl;
        if (i == 0) rowptr[0] = 0;
    }
}

// ---------------- prep ----------------
struct PrepAll {
    const float* src[7];
    ushort* dst[7];
    int K[7];
    int N[7];
    int off[8];
};

__launch_bounds__(256)
__global__ void wprep_kernel(PrepAll a) {
    const int b = blockIdx.x;
    int m = 0;
    while (m < 6 && b >= a.off[m + 1]) m++;
    const int K = a.K[m], N = a.N[m];
    const int e = (b - a.off[m]) * 256 + threadIdx.x;   // e = n*K + k
    if (e >= K * N) return;
    const int n = e / K, k = e % K;
    a.dst[m][e] = f2b(a.src[m][(size_t)k * N + n]);
}

__global__ void x2bf_kernel(const float* __restrict__ x, ushort* __restrict__ xb,
                            float* __restrict__ bn0, float* __restrict__ bn1, int total4) {
    if (blockIdx.x == 0 && threadIdx.x < 256) {
        bn0[threadIdx.x] = 0.f;
        bn1[threadIdx.x] = 0.f;
    }
    int i = blockIdx.x * 256 + threadIdx.x;
    if (i < total4) {
        float4 v = reinterpret_cast<const float4*>(x)[i];
        ushort4 o;
        o.x = f2b(v.x); o.y = f2b(v.y); o.z = f2b(v.z); o.w = f2b(v.w);
        reinterpret_cast<ushort4*>(xb)[i] = o;
    }
}

// ---------------- fused layer: agg -> GEMM1(relu) -> GEMM2 -> fp32 conv ----
// 512 threads = 8 waves; block handles 64 node rows.
// Zt/Yt LDS tiles XOR-swizzled: byte ^= (row&7)<<4 (kills row-stride conflicts).
template <int K1, int NC2>
__launch_bounds__(512)
__global__ void fused_layer(const ushort* __restrict__ table,
                            const int* __restrict__ rowptr, const int* __restrict__ csr,
                            const ushort* __restrict__ W1t, const float* __restrict__ b1,
                            const ushort* __restrict__ W2t, const float* __restrict__ b2,
                            float* __restrict__ conv, int M) {
    __shared__ ushort Zt[64 * K1];
    __shared__ ushort Yt[64 * 128];
    const int tid = threadIdx.x;
    const int w = tid >> 6, lane = tid & 63;
    const int rb0 = blockIdx.x * 64;
    constexpr int ZROWB = K1 * 2;   // bytes per Zt row

    // ---- stage 0: gather 8 rows per wave into swizzled Zt
    for (int i = 0; i < 8; i++) {
        const int r = w * 8 + i;
        const int nd = min(rb0 + r, M - 1);
        const int s = rowptr[nd], e = rowptr[nd + 1];
        if constexpr (K1 == 128) {
            const uint* t2 = reinterpret_cast<const uint*>(table);
            uint v = t2[(size_t)nd * 64 + lane];
            float ax = lo16(v), ay = hi16(v);
#pragma unroll 4
            for (int k = s; k < e; k++) {
                uint u = t2[(size_t)csr[k] * 64 + lane];
                ax += lo16(u);
                ay += hi16(u);
            }
            const uint boff = (uint)(r * 256 + lane * 4) ^ ((r & 7) << 4);
            *reinterpret_cast<uint*>(reinterpret_cast<char*>(Zt) + boff) = packbf(ax, ay);
        } else {
            float a = b2f(table[(size_t)nd * 64 + lane]);
#pragma unroll 4
            for (int k = s; k < e; k++) a += b2f(table[(size_t)csr[k] * 64 + lane]);
            const uint boff = (uint)(r * 128 + lane * 2) ^ ((r & 7) << 4);
            *reinterpret_cast<ushort*>(reinterpret_cast<char*>(Zt) + boff) = f2b(a);
        }
    }
    __syncthreads();

    // ---- stage 1: Y1 = relu(Z @ W1 + b1) -> swizzled Yt (bf16)
    const int wr = w >> 2, wc = w & 3;          // 2 x 4 wave tiling, 32x32 each
    const int lr = lane & 15, hi = lane >> 4;
    const int xorv = (lr & 7) << 4;             // (row&7)<<4 for rows ar=32*wr{+16}+lr
    {
        f32x4 a00 = {}, a01 = {}, a10 = {}, a11 = {};
#pragma unroll
        for (int k0 = 0; k0 < K1; k0 += 32) {
            const uint o0 = (uint)((wr * 32 + lr) * ZROWB + k0 * 2 + hi * 16) ^ xorv;
            const uint o1 = (uint)((wr * 32 + 16 + lr) * ZROWB + k0 * 2 + hi * 16) ^ xorv;
            bf16x8 za0 = *reinterpret_cast<const bf16x8*>(reinterpret_cast<const char*>(Zt) + o0);
            bf16x8 za1 = *reinterpret_cast<const bf16x8*>(reinterpret_cast<const char*>(Zt) + o1);
            bf16x8 wb0 = *reinterpret_cast<const bf16x8*>(W1t + (size_t)(wc * 32 + lr) * K1 + k0 + hi * 8);
            bf16x8 wb1 = *reinterpret_cast<const bf16x8*>(W1t + (size_t)(wc * 32 + 16 + lr) * K1 + k0 + hi * 8);
            a00 = __builtin_amdgcn_mfma_f32_16x16x32_bf16(za0, wb0, a00, 0, 0, 0);
            a01 = __builtin_amdgcn_mfma_f32_16x16x32_bf16(za0, wb1, a01, 0, 0, 0);
            a10 = __builtin_amdgcn_mfma_f32_16x16x32_bf16(za1, wb0, a10, 0, 0, 0);
            a11 = __builtin_amdgcn_mfma_f32_16x16x32_bf16(za1, wb1, a11, 0, 0, 0);
        }
        const int orow = hi * 4;
        const int c0 = wc * 32 + lr, c1 = wc * 32 + 16 + lr;
        const float bv0 = b1[c0], bv1 = b1[c1];
        f32x4 accs[2][2] = {{a00, a01}, {a10, a11}};
#pragma unroll
        for (int m = 0; m < 2; m++) {
#pragma unroll
            for (int j = 0; j < 4; j++) {
                const int row = wr * 32 + m * 16 + orow + j;
                const uint bo0 = (uint)(row * 256 + c0 * 2) ^ ((row & 7) << 4);
                const uint bo1 = (uint)(row * 256 + c1 * 2) ^ ((row & 7) << 4);
                *reinterpret_cast<ushort*>(reinterpret_cast<char*>(Yt) + bo0) = f2b(fmaxf(accs[m][0][j] + bv0, 0.f));
                *reinterpret_cast<ushort*>(reinterpret_cast<char*>(Yt) + bo1) = f2b(fmaxf(accs[m][1][j] + bv1, 0.f));
            }
        }
    }
    __syncthreads();

    // ---- stage 2: conv = Y1 @ W2 + b2 -> fp32 global
    if (NC2 == 128 || w < 2) {
        const int wr2 = (NC2 == 128) ? (w >> 2) : w;
        const int wc2 = (NC2 == 128) ? (w & 3) : 0;
        f32x4 d00 = {}, d01 = {}, d10 = {}, d11 = {};
#pragma unroll
        for (int k0 = 0; k0 < 128; k0 += 32) {
            const uint o0 = (uint)((wr2 * 32 + lr) * 256 + k0 * 2 + hi * 16) ^ xorv;
            const uint o1 = (uint)((wr2 * 32 + 16 + lr) * 256 + k0 * 2 + hi * 16) ^ xorv;
            bf16x8 ya0 = *reinterpret_cast<const bf16x8*>(reinterpret_cast<const char*>(Yt) + o0);
            bf16x8 ya1 = *reinterpret_cast<const bf16x8*>(reinterpret_cast<const char*>(Yt) + o1);
            bf16x8 wb0 = *reinterpret_cast<const bf16x8*>(W2t + (size_t)(wc2 * 32 + lr) * 128 + k0 + hi * 8);
            bf16x8 wb1 = *reinterpret_cast<const bf16x8*>(W2t + (size_t)(wc2 * 32 + 16 + lr) * 128 + k0 + hi * 8);
            d00 = __builtin_amdgcn_mfma_f32_16x16x32_bf16(ya0, wb0, d00, 0, 0, 0);
            d01 = __builtin_amdgcn_mfma_f32_16x16x32_bf16(ya0, wb1, d01, 0, 0, 0);
            d10 = __builtin_amdgcn_mfma_f32_16x16x32_bf16(ya1, wb0, d10, 0, 0, 0);
            d11 = __builtin_amdgcn_mfma_f32_16x16x32_bf16(ya1, wb1, d11, 0, 0, 0);
        }
        const int orow = hi * 4;
        const int c0 = wc2 * 32 + lr, c1 = wc2 * 32 + 16 + lr;
        const float bv0 = b2[c0], bv1 = b2[c1];
        f32x4 accs[2][2] = {{d00, d01}, {d10, d11}};
#pragma unroll
        for (int m = 0; m < 2; m++) {
#pragma unroll
            for (int j = 0; j < 4; j++) {
                const int row = rb0 + wr2 * 32 + m * 16 + orow + j;
                if (row < M) {
                    conv[(size_t)row * NC2 + c0] = accs[m][0][j] + bv0;
                    conv[(size_t)row * NC2 + c1] = accs[m][1][j] + bv1;
                }
            }
        }
    }
}

// ---------------- standalone MFMA GEMM (skip projection) ----------------
template <int K, int NC, int WR, int WC, bool RELU>
__launch_bounds__(256)
__global__ void mfma_gemm(const ushort* __restrict__ A, const ushort* __restrict__ Wt,
                          const float* __restrict__ bias, float* __restrict__ Cf, int M) {
    constexpr int BM = WR * 32;
    const int tid = threadIdx.x;
    const int w = tid >> 6, lane = tid & 63;
    const int wr = w / WC, wc = w % WC;
    const int rb = blockIdx.x * BM + wr * 32;
    const int cb = blockIdx.y * (WC * 32) + wc * 32;
    const int lr = lane & 15;
    const int lk = (lane >> 4) * 8;

    int ar0 = min(rb + lr, M - 1);
    int ar1 = min(rb + 16 + lr, M - 1);
    const int br0 = cb + lr;
    const int br1 = cb + 16 + lr;

    f32x4 acc00 = {}, acc01 = {}, acc10 = {}, acc11 = {};
#pragma unroll
    for (int k0 = 0; k0 < K; k0 += 32) {
        bf16x8 a0 = *reinterpret_cast<const bf16x8*>(A + (size_t)ar0 * K + k0 + lk);
        bf16x8 a1 = *reinterpret_cast<const bf16x8*>(A + (size_t)ar1 * K + k0 + lk);
        bf16x8 b0 = *reinterpret_cast<const bf16x8*>(Wt + (size_t)br0 * K + k0 + lk);
        bf16x8 b1 = *reinterpret_cast<const bf16x8*>(Wt + (size_t)br1 * K + k0 + lk);
        acc00 = __builtin_amdgcn_mfma_f32_16x16x32_bf16(a0, b0, acc00, 0, 0, 0);
        acc01 = __builtin_amdgcn_mfma_f32_16x16x32_bf16(a0, b1, acc01, 0, 0, 0);
        acc10 = __builtin_amdgcn_mfma_f32_16x16x32_bf16(a1, b0, acc10, 0, 0, 0);
        acc11 = __builtin_amdgcn_mfma_f32_16x16x32_bf16(a1, b1, acc11, 0, 0, 0);
    }

    const int orow = (lane >> 4) * 4;
    const int col0 = cb + lr, col1 = cb + 16 + lr;
    const float bv0 = bias[col0], bv1 = bias[col1];
    f32x4 accs[2][2] = {{acc00, acc01}, {acc10, acc11}};
#pragma unroll
    for (int m = 0; m < 2; m++) {
#pragma unroll
        for (int j = 0; j < 4; j++) {
            const int row = rb + m * 16 + orow + j;
            if (row < M) {
                float v0 = accs[m][0][j] + bv0;
                float v1 = accs[m][1][j] + bv1;
                if (RELU) { v0 = fmaxf(v0, 0.f); v1 = fmaxf(v1, 0.f); }
                Cf[(size_t)row * NC + col0] = v0;
                Cf[(size_t)row * NC + col1] = v1;
            }
        }
    }
}

// ---------------- batchnorm ----------------
__launch_bounds__(256)
__global__ void bn_stats_kernel(const float* __restrict__ h, float* __restrict__ sums, int n) {
    __shared__ float ls[256], lq[256];
    const int tid = threadIdx.x;
    const int c = tid & 127;
    const int rpb = (n + gridDim.x - 1) / gridDim.x;
    const int rend = min(n, (int)(blockIdx.x + 1) * rpb);
    float s = 0.f, q = 0.f;
    for (int r = blockIdx.x * rpb + (tid >> 7); r < rend; r += 2) {
        float v = h[(size_t)r * HID + c];
        s += v;
        q += v * v;
    }
    ls[tid] = s; lq[tid] = q;
    __syncthreads();
    if (tid < 128) {
        atomicAdd(&sums[c], ls[tid] + ls[tid + 128]);
        atomicAdd(&sums[128 + c], lq[tid] + lq[tid + 128]);
    }
}

template <bool WRITE_RES>
__global__ void bn_apply_kernel(const float* __restrict__ conv, const float* __restrict__ sums,
                                const float* __restrict__ gamma, const float* __restrict__ beta,
                                const float* __restrict__ add, float* __restrict__ resf,
                                ushort* __restrict__ outb, int total, int n) {
    int i = blockIdx.x * blockDim.x + threadIdx.x;
    if (i >= total) return;
    int c = i & (HID - 1);
    float m = sums[c] / (float)n;
    float v = sums[HID + c] / (float)n - m * m;
    float sc = gamma[c] * rsqrtf(v + 1e-5f);
    float val = (conv[i] - m) * sc + beta[c] + add[i];
    if (WRITE_RES) resf[i] = val;
    outb[i] = f2b(fmaxf(val, 0.f));
}

extern "C" void kernel_launch(void* const* d_in, const int* in_sizes, int n_in,
                              void* d_out, int out_size, void* d_ws, size_t ws_size,
                              hipStream_t stream) {
    const float* x      = (const float*)d_in[0];
    const int*   ei     = (const int*)d_in[1];
    const float* w1_0   = (const float*)d_in[2];
    const float* b1_0   = (const float*)d_in[3];
    const float* w2_0   = (const float*)d_in[4];
    const float* b2_0   = (const float*)d_in[5];
    const float* skip_w = (const float*)d_in[6];
    const float* skip_b = (const float*)d_in[7];
    const float* bn_g0  = (const float*)d_in[8];
    const float* bn_b0  = (const float*)d_in[9];
    const float* w1_1   = (const float*)d_in[10];
    const float* b1_1   = (const float*)d_in[11];
    const float* w2_1   = (const float*)d_in[12];
    const float* b2_1   = (const float*)d_in[13];
    const float* bn_g1  = (const float*)d_in[14];
    const float* bn_b1  = (const float*)d_in[15];
    const float* w1_2   = (const float*)d_in[16];
    const float* b1_2   = (const float*)d_in[17];
    const float* w2_2   = (const float*)d_in[18];
    const float* b2_2   = (const float*)d_in[19];

    const int N = in_sizes[0] / 64;
    const int E = in_sizes[1] / 2;
    const int pchunk = (N + NPART - 1) / NPART;

    char* p = (char*)d_ws;
    auto carve = [&](size_t bytes) -> void* {
        void* q = (void*)p;
        p += (bytes + 255) & ~(size_t)255;
        return q;
    };
    int*   cursor = (int*)carve((size_t)N * 4);
    int*   rowptr = (int*)carve((size_t)(N + 1) * 4);
    int*   csr    = (int*)carve((size_t)E * 4);
    int*   bsum   = (int*)carve(1024 * 4);
    int*   bc     = (int*)carve((size_t)NPART * ABLK * 4);
    int2*  ebuf   = (int2*)carve((size_t)E * 8);
    float* bnsums0 = (float*)carve(256 * 4);
    float* bnsums1 = (float*)carve(256 * 4);
    ushort* w1_0t = (ushort*)carve(64 * 128 * 2);
    ushort* w2_0t = (ushort*)carve(128 * 128 * 2);
    ushort* skwt  = (ushort*)carve(64 * 128 * 2);
    ushort* w1_1t = (ushort*)carve(128 * 128 * 2);
    ushort* w2_1t = (ushort*)carve(128 * 128 * 2);
    ushort* w1_2t = (ushort*)carve(128 * 128 * 2);
    ushort* w2_2t = (ushort*)carve(128 * 32 * 2);
    ushort* x_bf  = (ushort*)carve((size_t)N * 64 * 2);
    ushort* aggin = (ushort*)carve((size_t)N * HID * 2);   // relu'd bf16 node table
    float* bufA_f = (float*)carve((size_t)N * HID * 4);    // conv (fp32, for BN)
    float* bufC_f = (float*)carve((size_t)N * HID * 4);    // skip -> residual

    const int NB  = (N + 255) / 256;
    const int EWB = (N * HID + 255) / 256;
    const int FUSE_G = (N + 63) / 64;
    const dim3 G128((N + 63) / 64, 2);   // skip gemm: 64 rows x 64 cols per block

    // ---- prep
    PrepAll pa;
    pa.src[0] = w1_0; pa.dst[0] = w1_0t; pa.K[0] = 64;  pa.N[0] = 128;
    pa.src[1] = w2_0; pa.dst[1] = w2_0t; pa.K[1] = 128; pa.N[1] = 128;
    pa.src[2] = skip_w; pa.dst[2] = skwt; pa.K[2] = 64; pa.N[2] = 128;
    pa.src[3] = w1_1; pa.dst[3] = w1_1t; pa.K[3] = 128; pa.N[3] = 128;
    pa.src[4] = w2_1; pa.dst[4] = w2_1t; pa.K[4] = 128; pa.N[4] = 128;
    pa.src[5] = w1_2; pa.dst[5] = w1_2t; pa.K[5] = 128; pa.N[5] = 128;
    pa.src[6] = w2_2; pa.dst[6] = w2_2t; pa.K[6] = 128; pa.N[6] = 32;
    int off = 0;
    for (int m = 0; m < 7; m++) { pa.off[m] = off; off += (pa.K[m] * pa.N[m]) / 256; }
    pa.off[7] = off;
    wprep_kernel<<<off, 256, 0, stream>>>(pa);
    x2bf_kernel<<<(N * 64 / 4 + 255) / 256, 256, 0, stream>>>(x, x_bf, bnsums0, bnsums1, N * 64 / 4);

    // ---- CSR build
    hipMemsetAsync(cursor, 0, (size_t)N * 4, stream);
    ecount_kernel<<<ABLK, 256, 0, stream>>>(ei, bc, E, pchunk);
    escan_kernel<<<1, 1024, 0, stream>>>(bc);
    edist_kernel<<<ABLK, 256, 0, stream>>>(ei, bc, ebuf, E, pchunk);
    histp_kernel<<<NPART * BBLK, 256, 0, stream>>>(ebuf, bc, cursor, E);
    bsum_kernel<<<NB, 256, 0, stream>>>(cursor, bsum, N);
    bscan_kernel<<<1, 1024, 0, stream>>>(bsum, NB);
    lscan_kernel<<<NB, 256, 0, stream>>>(bsum, cursor, rowptr, N);
    scatterp_kernel<<<NPART * BBLK, 256, 0, stream>>>(ebuf, bc, cursor, csr, E);

    // ---- layer 0
    fused_layer<64, 128><<<FUSE_G, 512, 0, stream>>>(x_bf, rowptr, csr, w1_0t, b1_0, w2_0t, b2_0, bufA_f, N);
    mfma_gemm<64, 128, 2, 2, false><<<G128, 256, 0, stream>>>(x_bf, skwt, skip_b, bufC_f, N);
    bn_stats_kernel<<<256, 256, 0, stream>>>(bufA_f, bnsums0, N);
    bn_apply_kernel<true><<<EWB, 256, 0, stream>>>(bufA_f, bnsums0, bn_g0, bn_b0, bufC_f, bufC_f, aggin, N * HID, N);

    // ---- layer 1
    fused_layer<128, 128><<<FUSE_G, 512, 0, stream>>>(aggin, rowptr, csr, w1_1t, b1_1, w2_1t, b2_1, bufA_f, N);
    bn_stats_kernel<<<256, 256, 0, stream>>>(bufA_f, bnsums1, N);
    bn_apply_kernel<false><<<EWB, 256, 0, stream>>>(bufA_f, bnsums1, bn_g1, bn_b1, bufC_f, nullptr, aggin, N * HID, N);

    // ---- layer 2
    fused_layer<128, 32><<<FUSE_G, 512, 0, stream>>>(aggin, rowptr, csr, w1_2t, b1_2, w2_2t, b2_2, (float*)d_out, N);
}

// Round 6
// 340.366 us; speedup vs baseline: 2.1245x; 1.0475x over previous
//
#include <hip/hip_runtime.h>
#include <hip/hip_bf16.h>

// ---------------------------------------------------------------------------
// GIN (3-layer) forward on MI355X.
//  - CSR build: 3-pass edge bucketing into 8 dst partitions, partition-local
//    hist/scatter (XCD-L2-local atomics).
//  - Per layer: ONE fused kernel (gather agg -> MFMA GEMM1+relu -> MFMA GEMM2
//    [+ fused skip GEMM on layer 0]) with 32-row blocks / 256 thr so the whole
//    grid is resident (latency hiding by TLP). conv in bf16 (fp32 for d_out).
// ---------------------------------------------------------------------------

#define HID 128
#define NPART 8
#define ABLK 256      // blocks in edge-bucketing passes
#define BBLK 128      // blocks per partition in hist/scatter

typedef __attribute__((ext_vector_type(8))) __bf16 bf16x8;
typedef __attribute__((ext_vector_type(4))) float f32x4;

__device__ __forceinline__ ushort f2b(float f) {
    uint u = __builtin_bit_cast(uint, f);
    u = (u + 0x7fffu + ((u >> 16) & 1u)) >> 16;
    return (ushort)u;
}
__device__ __forceinline__ float b2f(ushort s) {
    return __builtin_bit_cast(float, (uint)s << 16);
}
__device__ __forceinline__ float lo16(uint u) { return __builtin_bit_cast(float, u << 16); }
__device__ __forceinline__ float hi16(uint u) { return __builtin_bit_cast(float, u & 0xffff0000u); }
__device__ __forceinline__ uint packbf(float a, float b) {
    return (uint)f2b(a) | ((uint)f2b(b) << 16);
}

// ---------------- CSR build ----------------
__launch_bounds__(256)
__global__ void ecount_kernel(const int* __restrict__ ei, int* __restrict__ bc,
                              int E, int pchunk) {
    __shared__ int cnt[NPART];
    if (threadIdx.x < NPART) cnt[threadIdx.x] = 0;
    __syncthreads();
    const int epb = (E + ABLK - 1) / ABLK;
    const int e0 = blockIdx.x * epb, e1 = min(e0 + epb, E);
    for (int e = e0 + threadIdx.x; e < e1; e += 256) {
        int d = ei[E + e];
        atomicAdd(&cnt[d / pchunk], 1);
    }
    __syncthreads();
    if (threadIdx.x < NPART) bc[threadIdx.x * ABLK + blockIdx.x] = cnt[threadIdx.x];
}

__launch_bounds__(1024)
__global__ void escan_kernel(int* __restrict__ bc) {
    __shared__ int ls[1024];
    const int t = threadIdx.x;
    const int v0 = bc[2 * t], v1 = bc[2 * t + 1];
    ls[t] = v0 + v1;
    __syncthreads();
    for (int off = 1; off < 1024; off <<= 1) {
        int tmp = (t >= off) ? ls[t - off] : 0;
        __syncthreads();
        ls[t] += tmp;
        __syncthreads();
    }
    const int excl = ls[t] - (v0 + v1);
    bc[2 * t] = excl;
    bc[2 * t + 1] = excl + v0;
}

__launch_bounds__(256)
__global__ void edist_kernel(const int* __restrict__ ei, const int* __restrict__ bc,
                             int2* __restrict__ ebuf, int E, int pchunk) {
    __shared__ int base[NPART];
    if (threadIdx.x < NPART) base[threadIdx.x] = bc[threadIdx.x * ABLK + blockIdx.x];
    __syncthreads();
    const int epb = (E + ABLK - 1) / ABLK;
    const int e0 = blockIdx.x * epb, e1 = min(e0 + epb, E);
    for (int e = e0 + threadIdx.x; e < e1; e += 256) {
        int s = ei[e], d = ei[E + e];
        int pos = atomicAdd(&base[d / pchunk], 1);
        ebuf[pos] = make_int2(s, d);
    }
}

__launch_bounds__(256)
__global__ void histp_kernel(const int2* __restrict__ ebuf, const int* __restrict__ bc,
                             int* __restrict__ deg, int E) {
    const int part = blockIdx.x & (NPART - 1);
    const int blk  = blockIdx.x >> 3;
    const int pstart = bc[part * ABLK];
    const int pend = (part == NPART - 1) ? E : bc[(part + 1) * ABLK];
    const int epb = (pend - pstart + BBLK - 1) / BBLK;
    const int e0 = pstart + blk * epb, e1 = min(e0 + epb, pend);
    for (int e = e0 + threadIdx.x; e < e1; e += 256)
        atomicAdd(&deg[ebuf[e].y], 1);
}

__launch_bounds__(256)
__global__ void scatterp_kernel(const int2* __restrict__ ebuf, const int* __restrict__ bc,
                                int* __restrict__ cursor, int* __restrict__ csr_src, int E) {
    const int part = blockIdx.x & (NPART - 1);
    const int blk  = blockIdx.x >> 3;
    const int pstart = bc[part * ABLK];
    const int pend = (part == NPART - 1) ? E : bc[(part + 1) * ABLK];
    const int epb = (pend - pstart + BBLK - 1) / BBLK;
    const int e0 = pstart + blk * epb, e1 = min(e0 + epb, pend);
    for (int e = e0 + threadIdx.x; e < e1; e += 256) {
        int2 ed = ebuf[e];
        int p = atomicAdd(&cursor[ed.y], 1);
        csr_src[p] = ed.x;
    }
}

__launch_bounds__(256)
__global__ void bsum_kernel(const int* __restrict__ deg, int* __restrict__ bsum, int n) {
    __shared__ int ls[256];
    const int tid = threadIdx.x;
    const int i = blockIdx.x * 256 + tid;
    ls[tid] = (i < n) ? deg[i] : 0;
    __syncthreads();
    for (int off = 128; off > 0; off >>= 1) {
        if (tid < off) ls[tid] += ls[tid + off];
        __syncthreads();
    }
    if (tid == 0) bsum[blockIdx.x] = ls[0];
}

__launch_bounds__(1024)
__global__ void bscan_kernel(int* __restrict__ bsum, int nb) {
    __shared__ int ls[1024];
    const int tid = threadIdx.x;
    const int v = (tid < nb) ? bsum[tid] : 0;
    ls[tid] = v;
    __syncthreads();
    for (int off = 1; off < 1024; off <<= 1) {
        int t = (tid >= off) ? ls[tid - off] : 0;
        __syncthreads();
        ls[tid] += t;
        __syncthreads();
    }
    if (tid < nb) bsum[tid] = ls[tid] - v;   // exclusive
}

__launch_bounds__(256)
__global__ void lscan_kernel(const int* __restrict__ bsum, int* __restrict__ cursor,
                             int* __restrict__ rowptr, int n) {
    __shared__ int ls[256];
    const int tid = threadIdx.x;
    const int i = blockIdx.x * 256 + tid;
    const int v = (i < n) ? cursor[i] : 0;
    ls[tid] = v;
    __syncthreads();
    for (int off = 1; off < 256; off <<= 1) {
        int t = (tid >= off) ? ls[tid - off] : 0;
        __syncthreads();
        ls[tid] += t;
        __syncthreads();
    }
    if (i < n) {
        const int incl = ls[tid] + bsum[blockIdx.x];
        cursor[i] = incl - v;
        rowptr[i + 1] = incl;
        if (i == 0) rowptr[0] = 0;
    }
}

// ---------------- prep ----------------
struct PrepAll {
    const float* src[7];
    ushort* dst[7];
    int K[7];
    int N[7];
    int off[8];
};

__launch_bounds__(256)
__global__ void wprep_kernel(PrepAll a) {
    const int b = blockIdx.x;
    int m = 0;
    while (m < 6 && b >= a.off[m + 1]) m++;
    const int K = a.K[m], N = a.N[m];
    const int e = (b - a.off[m]) * 256 + threadIdx.x;   // e = n*K + k
    if (e >= K * N) return;
    const int n = e / K, k = e % K;
    a.dst[m][e] = f2b(a.src[m][(size_t)k * N + n]);
}

__global__ void x2bf_kernel(const float* __restrict__ x, ushort* __restrict__ xb,
                            float* __restrict__ bn0, float* __restrict__ bn1, int total4) {
    if (blockIdx.x == 0 && threadIdx.x < 256) {
        bn0[threadIdx.x] = 0.f;
        bn1[threadIdx.x] = 0.f;
    }
    int i = blockIdx.x * 256 + threadIdx.x;
    if (i < total4) {
        float4 v = reinterpret_cast<const float4*>(x)[i];
        ushort4 o;
        o.x = f2b(v.x); o.y = f2b(v.y); o.z = f2b(v.z); o.w = f2b(v.w);
        reinterpret_cast<ushort4*>(xb)[i] = o;
    }
}

// ---------------- fused layer ----------------
// 256 thr = 4 waves; 32 node rows per block. Zt/Yt XOR-swizzled LDS.
// stages: gather -> GEMM1(relu) -> [x-load] GEMM2 -> [skip GEMM]
template <int K1, int NC2, bool SKIP, bool OUTBF>
__launch_bounds__(256)
__global__ void fused_layer(const ushort* __restrict__ table,
                            const int* __restrict__ rowptr, const int* __restrict__ csr,
                            const ushort* __restrict__ W1t, const float* __restrict__ b1,
                            const ushort* __restrict__ W2t, const float* __restrict__ b2,
                            float* __restrict__ convf, ushort* __restrict__ convb,
                            const ushort* __restrict__ skw, const float* __restrict__ skb,
                            float* __restrict__ skipout, int M) {
    __shared__ ushort Zt[32 * K1];
    __shared__ ushort Yt[32 * 128];
    const int tid = threadIdx.x;
    const int w = tid >> 6, lane = tid & 63;
    const int rb0 = blockIdx.x * 32;
    constexpr int ZROWB = K1 * 2;

    // ---- stage 0: gather -> swizzled Zt
    if constexpr (K1 == 128) {
        const uint* t2 = reinterpret_cast<const uint*>(table);
#pragma unroll
        for (int i = 0; i < 8; i++) {
            const int rt = w * 8 + i;
            const int nd = min(rb0 + rt, M - 1);
            const int s = rowptr[nd], e = rowptr[nd + 1];
            uint v = t2[(size_t)nd * 64 + lane];
            float ax = lo16(v), ay = hi16(v);
#pragma unroll 8
            for (int k = s; k < e; k++) {
                uint u = t2[(size_t)csr[k] * 64 + lane];
                ax += lo16(u);
                ay += hi16(u);
            }
            const uint boff = (uint)(rt * 256 + lane * 4) ^ ((rt & 7) << 4);
            *reinterpret_cast<uint*>(reinterpret_cast<char*>(Zt) + boff) = packbf(ax, ay);
        }
    } else {
        // two rows per wave-iteration (half-wave each, uint = 2 cols)
        const uint* t2 = reinterpret_cast<const uint*>(table);
        const int half = lane >> 5, li = lane & 31;
#pragma unroll
        for (int i = 0; i < 4; i++) {
            const int rt = w * 8 + i * 2 + half;
            const int nd = min(rb0 + rt, M - 1);
            const int s = rowptr[nd], e = rowptr[nd + 1];
            uint v = t2[(size_t)nd * 32 + li];
            float ax = lo16(v), ay = hi16(v);
#pragma unroll 8
            for (int k = s; k < e; k++) {
                uint u = t2[(size_t)csr[k] * 32 + li];
                ax += lo16(u);
                ay += hi16(u);
            }
            const uint boff = (uint)(rt * 128 + li * 4) ^ ((rt & 7) << 4);
            *reinterpret_cast<uint*>(reinterpret_cast<char*>(Zt) + boff) = packbf(ax, ay);
        }
    }
    __syncthreads();

    const int lr = lane & 15, hg = lane >> 4;
    const int xorv = (lr & 7) << 4;

    // ---- stage 1: Yt = relu(Z @ W1 + b1)
    {
        f32x4 a00 = {}, a01 = {}, a10 = {}, a11 = {};
#pragma unroll
        for (int k0 = 0; k0 < K1; k0 += 32) {
            const uint o0 = (uint)(lr * ZROWB + k0 * 2 + hg * 16) ^ xorv;
            const uint o1 = (uint)((16 + lr) * ZROWB + k0 * 2 + hg * 16) ^ xorv;
            bf16x8 za0 = *reinterpret_cast<const bf16x8*>(reinterpret_cast<const char*>(Zt) + o0);
            bf16x8 za1 = *reinterpret_cast<const bf16x8*>(reinterpret_cast<const char*>(Zt) + o1);
            bf16x8 wb0 = *reinterpret_cast<const bf16x8*>(W1t + (size_t)(w * 32 + lr) * K1 + k0 + hg * 8);
            bf16x8 wb1 = *reinterpret_cast<const bf16x8*>(W1t + (size_t)(w * 32 + 16 + lr) * K1 + k0 + hg * 8);
            a00 = __builtin_amdgcn_mfma_f32_16x16x32_bf16(za0, wb0, a00, 0, 0, 0);
            a01 = __builtin_amdgcn_mfma_f32_16x16x32_bf16(za0, wb1, a01, 0, 0, 0);
            a10 = __builtin_amdgcn_mfma_f32_16x16x32_bf16(za1, wb0, a10, 0, 0, 0);
            a11 = __builtin_amdgcn_mfma_f32_16x16x32_bf16(za1, wb1, a11, 0, 0, 0);
        }
        const int c0 = w * 32 + lr, c1 = w * 32 + 16 + lr;
        const float bv0 = b1[c0], bv1 = b1[c1];
        f32x4 accs[2][2] = {{a00, a01}, {a10, a11}};
#pragma unroll
        for (int m = 0; m < 2; m++) {
#pragma unroll
            for (int j = 0; j < 4; j++) {
                const int row = m * 16 + hg * 4 + j;
                const uint sw = (uint)((row & 7) << 4);
                *reinterpret_cast<ushort*>(reinterpret_cast<char*>(Yt) + ((uint)(row * 256 + c0 * 2) ^ sw)) =
                    f2b(fmaxf(accs[m][0][j] + bv0, 0.f));
                *reinterpret_cast<ushort*>(reinterpret_cast<char*>(Yt) + ((uint)(row * 256 + c1 * 2) ^ sw)) =
                    f2b(fmaxf(accs[m][1][j] + bv1, 0.f));
            }
        }
    }
    __syncthreads();

    // ---- optional: load raw x tile into Zt (consumed by skip GEMM below)
    if constexpr (SKIP) {
        const uint* x2 = reinterpret_cast<const uint*>(table);   // table == x_bf for layer 0
#pragma unroll
        for (int pp = 0; pp < 4; pp++) {
            const int rt = pp * 8 + (tid >> 5);
            const int cu = tid & 31;
            const int nd = min(rb0 + rt, M - 1);
            uint v = x2[(size_t)nd * 32 + cu];
            const uint boff = (uint)(rt * 128 + cu * 4) ^ ((rt & 7) << 4);
            *reinterpret_cast<uint*>(reinterpret_cast<char*>(Zt) + boff) = v;
        }
    }

    // ---- stage 2: conv = Yt @ W2 + b2
    if (NC2 == 128 || w == 0) {
        const int cb2 = (NC2 == 128) ? w * 32 : 0;
        f32x4 d00 = {}, d01 = {}, d10 = {}, d11 = {};
#pragma unroll
        for (int k0 = 0; k0 < 128; k0 += 32) {
            const uint o0 = (uint)(lr * 256 + k0 * 2 + hg * 16) ^ xorv;
            const uint o1 = (uint)((16 + lr) * 256 + k0 * 2 + hg * 16) ^ xorv;
            bf16x8 ya0 = *reinterpret_cast<const bf16x8*>(reinterpret_cast<const char*>(Yt) + o0);
            bf16x8 ya1 = *reinterpret_cast<const bf16x8*>(reinterpret_cast<const char*>(Yt) + o1);
            bf16x8 wb0 = *reinterpret_cast<const bf16x8*>(W2t + (size_t)(cb2 + lr) * 128 + k0 + hg * 8);
            bf16x8 wb1 = *reinterpret_cast<const bf16x8*>(W2t + (size_t)(cb2 + 16 + lr) * 128 + k0 + hg * 8);
            d00 = __builtin_amdgcn_mfma_f32_16x16x32_bf16(ya0, wb0, d00, 0, 0, 0);
            d01 = __builtin_amdgcn_mfma_f32_16x16x32_bf16(ya0, wb1, d01, 0, 0, 0);
            d10 = __builtin_amdgcn_mfma_f32_16x16x32_bf16(ya1, wb0, d10, 0, 0, 0);
            d11 = __builtin_amdgcn_mfma_f32_16x16x32_bf16(ya1, wb1, d11, 0, 0, 0);
        }
        const int c0 = cb2 + lr, c1 = cb2 + 16 + lr;
        const float bv0 = b2[c0], bv1 = b2[c1];
        f32x4 accs[2][2] = {{d00, d01}, {d10, d11}};
#pragma unroll
        for (int m = 0; m < 2; m++) {
#pragma unroll
            for (int j = 0; j < 4; j++) {
                const int row = rb0 + m * 16 + hg * 4 + j;
                if (row < M) {
                    const float v0 = accs[m][0][j] + bv0;
                    const float v1 = accs[m][1][j] + bv1;
                    if constexpr (OUTBF) {
                        convb[(size_t)row * NC2 + c0] = f2b(v0);
                        convb[(size_t)row * NC2 + c1] = f2b(v1);
                    } else {
                        convf[(size_t)row * NC2 + c0] = v0;
                        convf[(size_t)row * NC2 + c1] = v1;
                    }
                }
            }
        }
    }

    // ---- stage 3: skip = x @ skw + skb (fp32)
    if constexpr (SKIP) {
        __syncthreads();
        f32x4 s00 = {}, s01 = {}, s10 = {}, s11 = {};
#pragma unroll
        for (int k0 = 0; k0 < 64; k0 += 32) {
            const uint o0 = (uint)(lr * 128 + k0 * 2 + hg * 16) ^ xorv;
            const uint o1 = (uint)((16 + lr) * 128 + k0 * 2 + hg * 16) ^ xorv;
            bf16x8 za0 = *reinterpret_cast<const bf16x8*>(reinterpret_cast<const char*>(Zt) + o0);
            bf16x8 za1 = *reinterpret_cast<const bf16x8*>(reinterpret_cast<const char*>(Zt) + o1);
            bf16x8 wb0 = *reinterpret_cast<const bf16x8*>(skw + (size_t)(w * 32 + lr) * 64 + k0 + hg * 8);
            bf16x8 wb1 = *reinterpret_cast<const bf16x8*>(skw + (size_t)(w * 32 + 16 + lr) * 64 + k0 + hg * 8);
            s00 = __builtin_amdgcn_mfma_f32_16x16x32_bf16(za0, wb0, s00, 0, 0, 0);
            s01 = __builtin_amdgcn_mfma_f32_16x16x32_bf16(za0, wb1, s01, 0, 0, 0);
            s10 = __builtin_amdgcn_mfma_f32_16x16x32_bf16(za1, wb0, s10, 0, 0, 0);
            s11 = __builtin_amdgcn_mfma_f32_16x16x32_bf16(za1, wb1, s11, 0, 0, 0);
        }
        const int c0 = w * 32 + lr, c1 = w * 32 + 16 + lr;
        const float bv0 = skb[c0], bv1 = skb[c1];
        f32x4 accs[2][2] = {{s00, s01}, {s10, s11}};
#pragma unroll
        for (int m = 0; m < 2; m++) {
#pragma unroll
            for (int j = 0; j < 4; j++) {
                const int row = rb0 + m * 16 + hg * 4 + j;
                if (row < M) {
                    skipout[(size_t)row * 128 + c0] = accs[m][0][j] + bv0;
                    skipout[(size_t)row * 128 + c1] = accs[m][1][j] + bv1;
                }
            }
        }
    }
}

// ---------------- batchnorm (bf16 conv) ----------------
__launch_bounds__(256)
__global__ void bn_stats_kernel(const ushort* __restrict__ h, float* __restrict__ sums, int n) {
    __shared__ float4 ls[256];
    const int tid = threadIdx.x;
    const int cp = tid & 63;          // col pair (cols 2cp, 2cp+1)
    const int g = tid >> 6;           // 0..3 row groups
    const int rpb = (n + gridDim.x - 1) / gridDim.x;
    const int rend = min(n, (int)(blockIdx.x + 1) * rpb);
    const uint* h2 = reinterpret_cast<const uint*>(h);
    float s0 = 0.f, q0 = 0.f, s1 = 0.f, q1 = 0.f;
    for (int r = blockIdx.x * rpb + g; r < rend; r += 4) {
        uint u = h2[(size_t)r * 64 + cp];
        float a = lo16(u), b = hi16(u);
        s0 += a; q0 += a * a;
        s1 += b; q1 += b * b;
    }
    ls[tid] = make_float4(s0, q0, s1, q1);
    __syncthreads();
    if (tid < 64) {
        float4 t0 = ls[tid], t1 = ls[tid + 64], t2 = ls[tid + 128], t3 = ls[tid + 192];
        atomicAdd(&sums[2 * tid],       t0.x + t1.x + t2.x + t3.x);
        atomicAdd(&sums[2 * tid + 1],   t0.z + t1.z + t2.z + t3.z);
        atomicAdd(&sums[128 + 2 * tid],     t0.y + t1.y + t2.y + t3.y);
        atomicAdd(&sums[128 + 2 * tid + 1], t0.w + t1.w + t2.w + t3.w);
    }
}

template <bool WRITE_RES>
__global__ void bn_apply_kernel(const ushort* __restrict__ conv, const float* __restrict__ sums,
                                const float* __restrict__ gamma, const float* __restrict__ beta,
                                const float* __restrict__ add, float* __restrict__ resf,
                                ushort* __restrict__ outb, int total2, int n) {
    int i = blockIdx.x * blockDim.x + threadIdx.x;   // pair index
    if (i >= total2) return;
    const int c0 = (i & 63) * 2, c1 = c0 + 1;
    const float inv = 1.f / (float)n;
    const float m0 = sums[c0] * inv, m1 = sums[c1] * inv;
    const float v0 = sums[128 + c0] * inv - m0 * m0;
    const float v1 = sums[128 + c1] * inv - m1 * m1;
    const float sc0 = gamma[c0] * rsqrtf(v0 + 1e-5f);
    const float sc1 = gamma[c1] * rsqrtf(v1 + 1e-5f);
    const uint u = reinterpret_cast<const uint*>(conv)[i];
    const float2 ad = reinterpret_cast<const float2*>(add)[i];
    const float val0 = (lo16(u) - m0) * sc0 + beta[c0] + ad.x;
    const float val1 = (hi16(u) - m1) * sc1 + beta[c1] + ad.y;
    if (WRITE_RES) reinterpret_cast<float2*>(resf)[i] = make_float2(val0, val1);
    reinterpret_cast<uint*>(outb)[i] = packbf(fmaxf(val0, 0.f), fmaxf(val1, 0.f));
}

extern "C" void kernel_launch(void* const* d_in, const int* in_sizes, int n_in,
                              void* d_out, int out_size, void* d_ws, size_t ws_size,
                              hipStream_t stream) {
    const float* x      = (const float*)d_in[0];
    const int*   ei     = (const int*)d_in[1];
    const float* w1_0   = (const float*)d_in[2];
    const float* b1_0   = (const float*)d_in[3];
    const float* w2_0   = (const float*)d_in[4];
    const float* b2_0   = (const float*)d_in[5];
    const float* skip_w = (const float*)d_in[6];
    const float* skip_b = (const float*)d_in[7];
    const float* bn_g0  = (const float*)d_in[8];
    const float* bn_b0  = (const float*)d_in[9];
    const float* w1_1   = (const float*)d_in[10];
    const float* b1_1   = (const float*)d_in[11];
    const float* w2_1   = (const float*)d_in[12];
    const float* b2_1   = (const float*)d_in[13];
    const float* bn_g1  = (const float*)d_in[14];
    const float* bn_b1  = (const float*)d_in[15];
    const float* w1_2   = (const float*)d_in[16];
    const float* b1_2   = (const float*)d_in[17];
    const float* w2_2   = (const float*)d_in[18];
    const float* b2_2   = (const float*)d_in[19];

    const int N = in_sizes[0] / 64;
    const int E = in_sizes[1] / 2;
    const int pchunk = (N + NPART - 1) / NPART;

    char* p = (char*)d_ws;
    auto carve = [&](size_t bytes) -> void* {
        void* q = (void*)p;
        p += (bytes + 255) & ~(size_t)255;
        return q;
    };
    int*   cursor = (int*)carve((size_t)N * 4);
    int*   rowptr = (int*)carve((size_t)(N + 1) * 4);
    int*   csr    = (int*)carve((size_t)E * 4);
    int*   bsum   = (int*)carve(1024 * 4);
    int*   bc     = (int*)carve((size_t)NPART * ABLK * 4);
    int2*  ebuf   = (int2*)carve((size_t)E * 8);
    float* bnsums0 = (float*)carve(256 * 4);
    float* bnsums1 = (float*)carve(256 * 4);
    ushort* w1_0t = (ushort*)carve(64 * 128 * 2);
    ushort* w2_0t = (ushort*)carve(128 * 128 * 2);
    ushort* skwt  = (ushort*)carve(64 * 128 * 2);
    ushort* w1_1t = (ushort*)carve(128 * 128 * 2);
    ushort* w2_1t = (ushort*)carve(128 * 128 * 2);
    ushort* w1_2t = (ushort*)carve(128 * 128 * 2);
    ushort* w2_2t = (ushort*)carve(128 * 32 * 2);
    ushort* x_bf  = (ushort*)carve((size_t)N * 64 * 2);
    ushort* aggin = (ushort*)carve((size_t)N * HID * 2);   // relu'd bf16 node table
    ushort* convB = (ushort*)carve((size_t)N * HID * 2);   // conv (bf16, for BN)
    float* bufC_f = (float*)carve((size_t)N * HID * 4);    // skip -> residual

    const int NB  = (N + 255) / 256;
    const int EWB2 = (N * 64 + 255) / 256;
    const int FUSE_G = (N + 31) / 32;

    // ---- prep
    PrepAll pa;
    pa.src[0] = w1_0; pa.dst[0] = w1_0t; pa.K[0] = 64;  pa.N[0] = 128;
    pa.src[1] = w2_0; pa.dst[1] = w2_0t; pa.K[1] = 128; pa.N[1] = 128;
    pa.src[2] = skip_w; pa.dst[2] = skwt; pa.K[2] = 64; pa.N[2] = 128;
    pa.src[3] = w1_1; pa.dst[3] = w1_1t; pa.K[3] = 128; pa.N[3] = 128;
    pa.src[4] = w2_1; pa.dst[4] = w2_1t; pa.K[4] = 128; pa.N[4] = 128;
    pa.src[5] = w1_2; pa.dst[5] = w1_2t; pa.K[5] = 128; pa.N[5] = 128;
    pa.src[6] = w2_2; pa.dst[6] = w2_2t; pa.K[6] = 128; pa.N[6] = 32;
    int off = 0;
    for (int m = 0; m < 7; m++) { pa.off[m] = off; off += (pa.K[m] * pa.N[m]) / 256; }
    pa.off[7] = off;
    wprep_kernel<<<off, 256, 0, stream>>>(pa);
    x2bf_kernel<<<(N * 64 / 4 + 255) / 256, 256, 0, stream>>>(x, x_bf, bnsums0, bnsums1, N * 64 / 4);

    // ---- CSR build
    hipMemsetAsync(cursor, 0, (size_t)N * 4, stream);
    ecount_kernel<<<ABLK, 256, 0, stream>>>(ei, bc, E, pchunk);
    escan_kernel<<<1, 1024, 0, stream>>>(bc);
    edist_kernel<<<ABLK, 256, 0, stream>>>(ei, bc, ebuf, E, pchunk);
    histp_kernel<<<NPART * BBLK, 256, 0, stream>>>(ebuf, bc, cursor, E);
    bsum_kernel<<<NB, 256, 0, stream>>>(cursor, bsum, N);
    bscan_kernel<<<1, 1024, 0, stream>>>(bsum, NB);
    lscan_kernel<<<NB, 256, 0, stream>>>(bsum, cursor, rowptr, N);
    scatterp_kernel<<<NPART * BBLK, 256, 0, stream>>>(ebuf, bc, cursor, csr, E);

    // ---- layer 0 (conv + fused skip GEMM)
    fused_layer<64, 128, true, true><<<FUSE_G, 256, 0, stream>>>(
        x_bf, rowptr, csr, w1_0t, b1_0, w2_0t, b2_0, nullptr, convB, skwt, skip_b, bufC_f, N);
    bn_stats_kernel<<<256, 256, 0, stream>>>(convB, bnsums0, N);
    bn_apply_kernel<true><<<EWB2, 256, 0, stream>>>(convB, bnsums0, bn_g0, bn_b0, bufC_f, bufC_f, aggin, N * 64, N);

    // ---- layer 1
    fused_layer<128, 128, false, true><<<FUSE_G, 256, 0, stream>>>(
        aggin, rowptr, csr, w1_1t, b1_1, w2_1t, b2_1, nullptr, convB, nullptr, nullptr, nullptr, N);
    bn_stats_kernel<<<256, 256, 0, stream>>>(convB, bnsums1, N);
    bn_apply_kernel<false><<<EWB2, 256, 0, stream>>>(convB, bnsums1, bn_g1, bn_b1, bufC_f, nullptr, aggin, N * 64, N);

    // ---- layer 2
    fused_layer<128, 32, false, false><<<FUSE_G, 256, 0, stream>>>(
        aggin, rowptr, csr, w1_2t, b1_2, w2_2t, b2_2, (float*)d_out, nullptr, nullptr, nullptr, nullptr, N);
}